// Round 2
// baseline (170.843 us; speedup 1.0000x reference)
//
#include <hip/hip_runtime.h>
#include <hip/hip_bf16.h>
#include <cstdint>
#include <cstddef>

#define T_DIM 2048
#define C_DIM 1024
#define NH 16
#define HS 64
#define KSP 64

// QKV GEMM: 128x64 tile, BK=128, XOR-swizzled LDS, global_load_lds staging
#define GBM 128
#define GBN 64
#define GBK 128
// o-proj GEMM: 64x64 tile (512 blocks = 2/CU)
#define OBM 64
#define OBN 64

// attention tiling: 32 consecutive t's per block, one head per block.
// Union of top-64 selections over 32 consecutive t's has <= 64+31 = 95 rows
// (sel(t+1) \ sel(t) subset-of {t+1}), so K/V head-slices are gathered ONCE
// into LDS and reused by all 32 t's. 512 MB of global gather -> ~24 MB.
#define ATB 32
#define USLOT 96
#define KSTR 72  // LDS row stride in shorts (144 B) — breaks 128B bank alignment

typedef short short8 __attribute__((ext_vector_type(8)));
typedef float f32x4 __attribute__((ext_vector_type(4)));
typedef _Float16 half2_t __attribute__((ext_vector_type(2)));

__device__ __forceinline__ float bfu2f(unsigned short u) {
  unsigned v = ((unsigned)u) << 16;
  return __builtin_bit_cast(float, v);
}
__device__ __forceinline__ unsigned short f2bfu(float f) {
  unsigned u = __builtin_bit_cast(unsigned, f);
  unsigned r = (u + 0x7fffu + ((u >> 16) & 1u)) >> 16;
  return (unsigned short)r;
}
__device__ __forceinline__ unsigned short f2h(float f) {
  _Float16 h = (_Float16)f;
  return __builtin_bit_cast(unsigned short, h);
}
__device__ __forceinline__ float bflo(unsigned u) {
  return __builtin_bit_cast(float, u << 16);
}
__device__ __forceinline__ float bfhi(unsigned u) {
  return __builtin_bit_cast(float, u & 0xffff0000u);
}

__device__ __forceinline__ float dot2h(unsigned kbits, unsigned qbits, float acc) {
#if __has_builtin(__builtin_amdgcn_fdot2)
  return __builtin_amdgcn_fdot2(__builtin_bit_cast(half2_t, kbits),
                                __builtin_bit_cast(half2_t, qbits), acc, false);
#else
  half2_t kk = __builtin_bit_cast(half2_t, kbits);
  half2_t qq = __builtin_bit_cast(half2_t, qbits);
  return acc + (float)kk.x * (float)qq.x + (float)kk.y * (float)qq.y;
#endif
}

#define GLOAD_LDS16(gp, lp)                                                  \
  __builtin_amdgcn_global_load_lds(                                          \
      (const __attribute__((address_space(1))) void*)(gp),                   \
      (__attribute__((address_space(3))) void*)(lp), 16, 0, 0)

// ---- launch 1: key_scores (blocks [0,512)) + f32->bf16 conversion (rest) ----
#define NSCORE (T_DIM / 4)  // 512
#define NCONV ((T_DIM * C_DIM + 4 * C_DIM * C_DIM) / 4 / 256)  // 6144
__global__ __launch_bounds__(256) void convert_scores_kernel(
    const float* __restrict__ x, const float* __restrict__ Wq,
    const float* __restrict__ Wk, const float* __restrict__ Wv,
    const float* __restrict__ Wo, const float* __restrict__ Wks,
    const float* __restrict__ bks,
    unsigned short* __restrict__ xb, unsigned short* __restrict__ Wqb,
    unsigned short* __restrict__ Wkb, unsigned short* __restrict__ Wvb,
    unsigned short* __restrict__ Wob, float* __restrict__ scores) {
  if (blockIdx.x < NSCORE) {
    const int t = blockIdx.x * 4 + (threadIdx.x >> 6);
    const int lane = threadIdx.x & 63;
    const float* xrow = x + (size_t)t * C_DIM;
    float acc = 0.f;
    #pragma unroll 4
    for (int i = lane; i < C_DIM; i += 64)
      acc += xrow[i] * Wks[i];
    #pragma unroll
    for (int o = 32; o; o >>= 1) acc += __shfl_xor(acc, o);
    if (lane == 0) scores[t] = acc + bks[0];
    return;
  }
  const int i = (blockIdx.x - NSCORE) * 256 + threadIdx.x;
  const int NX4 = T_DIM * C_DIM / 4;
  const int NW4 = C_DIM * C_DIM / 4;
  const float* src;
  unsigned short* dst;
  int j = i;
  if (j < NX4) { src = x; dst = xb; }
  else {
    j -= NX4;
    int w = j / NW4;
    j -= w * NW4;
    src = (w == 0) ? Wq : (w == 1) ? Wk : (w == 2) ? Wv : Wo;
    dst = (w == 0) ? Wqb : (w == 1) ? Wkb : (w == 2) ? Wvb : Wob;
  }
  float4 f = reinterpret_cast<const float4*>(src)[j];
  ushort4 o;
  o.x = f2bfu(f.x); o.y = f2bfu(f.y); o.z = f2bfu(f.z); o.w = f2bfu(f.w);
  reinterpret_cast<ushort4*>(dst)[j] = o;
}

// ---- GEMM body: 128x64 tile, BK=128; LDS passed in (shared arena) ----
__device__ __forceinline__ void gemm_body_128x64(
    const unsigned short* __restrict__ A, const unsigned short* __restrict__ W,
    f32x4 acc[4][2], int bm, int bn, int tid,
    unsigned short* As, unsigned short* Ws) {
  const int w = tid >> 6, lane = tid & 63;
  const int quad = lane >> 4, r = lane & 15;
  const int wm = (w >> 1) * 64, wn = (w & 1) * 32;
  const int sub = lane >> 4;
  const int c = lane & 15;
  const unsigned short* Arow[8];
  const unsigned short* Wrow[4];
  #pragma unroll
  for (int i = 0; i < 8; ++i) {
    const int row = w * 32 + i * 4 + sub;
    Arow[i] = A + (size_t)(bm * GBM + row) * C_DIM + ((c ^ (row & 7)) * 8);
  }
  #pragma unroll
  for (int i = 0; i < 4; ++i) {
    const int row = w * 16 + i * 4 + sub;
    Wrow[i] = W + (size_t)(bn * GBN + row) * C_DIM + ((c ^ (row & 7)) * 8);
  }
  for (int kb = 0; kb < C_DIM; kb += GBK) {
    #pragma unroll
    for (int i = 0; i < 8; ++i)
      GLOAD_LDS16(Arow[i] + kb, &As[(w * 32 + i * 4) * GBK]);
    #pragma unroll
    for (int i = 0; i < 4; ++i)
      GLOAD_LDS16(Wrow[i] + kb, &Ws[(w * 16 + i * 4) * GBK]);
    __syncthreads();
    #pragma unroll
    for (int ks = 0; ks < 4; ++ks) {
      const int pc = ((ks * 4 + quad) ^ (r & 7)) * 8;
      short8 af[4], bfr[2];
      #pragma unroll
      for (int mi = 0; mi < 4; ++mi)
        af[mi] = *reinterpret_cast<const short8*>(&As[(wm + mi * 16 + r) * GBK + pc]);
      #pragma unroll
      for (int ni = 0; ni < 2; ++ni)
        bfr[ni] = *reinterpret_cast<const short8*>(&Ws[(wn + ni * 16 + r) * GBK + pc]);
      #pragma unroll
      for (int mi = 0; mi < 4; ++mi)
        #pragma unroll
        for (int ni = 0; ni < 2; ++ni)
          acc[mi][ni] = __builtin_amdgcn_mfma_f32_16x16x32_bf16(af[mi], bfr[ni], acc[mi][ni], 0, 0, 0);
    }
    __syncthreads();
  }
}

// ---- launch 2: rank_sort (blocks [0,512)) + fused QKV GEMM (rest). ----
#define NRANK (T_DIM / 4)  // 512
__global__ __launch_bounds__(256) void gemm_qkv_rank_kernel(
    const unsigned short* __restrict__ A,
    const unsigned short* __restrict__ Wq, const unsigned short* __restrict__ Wk,
    const unsigned short* __restrict__ Wv,
    const float* __restrict__ bq, const float* __restrict__ bk,
    const float* __restrict__ bv,
    unsigned short* __restrict__ qo, unsigned short* __restrict__ ko,
    unsigned short* __restrict__ vo,
    const float* __restrict__ scores, int* __restrict__ sorted_idx) {
  __shared__ unsigned short lds[(GBM + GBN) * GBK];  // 48 KB arena
  const int tid = threadIdx.x;
  if (blockIdx.x < NRANK) {
    // rank-by-counting sort: one wave per element, lane-parallel scan
    float* ss = reinterpret_cast<float*>(lds);  // first 8 KB of arena
    for (int j = tid; j < T_DIM; j += 256) ss[j] = scores[j];
    __syncthreads();
    const int w = tid >> 6, lane = tid & 63;
    const int i = blockIdx.x * 4 + w;
    const float si = ss[i];
    int rank = 0;
    #pragma unroll
    for (int step = 0; step < T_DIM / 64; ++step) {
      const int j = step * 64 + lane;
      const float sj = ss[j];
      rank += (int)((sj > si) || (sj == si && j < i));
    }
    #pragma unroll
    for (int o = 32; o; o >>= 1) rank += __shfl_xor(rank, o);
    if (lane == 0) sorted_idx[rank] = i;
    return;
  }
  const int bid = blockIdx.x - NRANK;
  const int per = (T_DIM / GBM) * (C_DIM / GBN);  // 256
  const int which = bid / per;
  const int rem = bid % per;
  const int bm = rem / (C_DIM / GBN);
  const int bn = rem % (C_DIM / GBN);
  const unsigned short* W = (which == 0) ? Wq : (which == 1) ? Wk : Wv;
  const float* bias = (which == 0) ? bq : (which == 1) ? bk : bv;
  unsigned short* out = (which == 0) ? qo : (which == 1) ? ko : vo;
  f32x4 acc[4][2] = {};
  gemm_body_128x64(A, W, acc, bm, bn, tid, lds, lds + GBM * GBK);
  const int w = tid >> 6, lane = tid & 63;
  const int quad = lane >> 4, r = lane & 15;
  const int wm = (w >> 1) * 64, wn = (w & 1) * 32;
  #pragma unroll
  for (int mi = 0; mi < 4; ++mi) {
    #pragma unroll
    for (int ni = 0; ni < 2; ++ni) {
      const int col = bn * GBN + wn + ni * 16 + r;
      const float bf = bias[col];
      #pragma unroll
      for (int i = 0; i < 4; ++i) {
        const int row = bm * GBM + wm + mi * 16 + quad * 4 + i;
        const float val = acc[mi][ni][i] + bf;
        // q,k -> f16 (fdot2 path in attn); v -> bf16
        out[(size_t)row * C_DIM + col] = (which == 2) ? f2bfu(val) : f2h(val);
      }
    }
  }
}

// ---- o-proj GEMM body: 64x64 tile, BK=128 ----
__device__ __forceinline__ void gemm_body_64x64(
    const unsigned short* __restrict__ A, const unsigned short* __restrict__ W,
    f32x4 acc[2][2], int bm, int bn, int tid) {
  __shared__ unsigned short As[OBM * GBK];  // 16 KB
  __shared__ unsigned short Ws[OBN * GBK];  // 16 KB
  const int w = tid >> 6, lane = tid & 63;
  const int quad = lane >> 4, r = lane & 15;
  const int wm = (w >> 1) * 32, wn = (w & 1) * 32;
  const int sub = lane >> 4;
  const int c = lane & 15;
  const unsigned short* Arow[4];
  const unsigned short* Wrow[4];
  #pragma unroll
  for (int i = 0; i < 4; ++i) {
    const int row = w * 16 + i * 4 + sub;
    Arow[i] = A + (size_t)(bm * OBM + row) * C_DIM + ((c ^ (row & 7)) * 8);
    Wrow[i] = W + (size_t)(bn * OBN + row) * C_DIM + ((c ^ (row & 7)) * 8);
  }
  for (int kb = 0; kb < C_DIM; kb += GBK) {
    #pragma unroll
    for (int i = 0; i < 4; ++i)
      GLOAD_LDS16(Arow[i] + kb, &As[(w * 16 + i * 4) * GBK]);
    #pragma unroll
    for (int i = 0; i < 4; ++i)
      GLOAD_LDS16(Wrow[i] + kb, &Ws[(w * 16 + i * 4) * GBK]);
    __syncthreads();
    #pragma unroll
    for (int ks = 0; ks < 4; ++ks) {
      const int pc = ((ks * 4 + quad) ^ (r & 7)) * 8;
      short8 af[2], bfr[2];
      #pragma unroll
      for (int mi = 0; mi < 2; ++mi)
        af[mi] = *reinterpret_cast<const short8*>(&As[(wm + mi * 16 + r) * GBK + pc]);
      #pragma unroll
      for (int ni = 0; ni < 2; ++ni)
        bfr[ni] = *reinterpret_cast<const short8*>(&Ws[(wn + ni * 16 + r) * GBK + pc]);
      #pragma unroll
      for (int mi = 0; mi < 2; ++mi)
        #pragma unroll
        for (int ni = 0; ni < 2; ++ni)
          acc[mi][ni] = __builtin_amdgcn_mfma_f32_16x16x32_bf16(af[mi], bfr[ni], acc[mi][ni], 0, 0, 0);
    }
    __syncthreads();
  }
}

// ---- launch 5: output projection GEMM, fp32 out, 64x64 tile ----
__global__ __launch_bounds__(256) void gemm_o_f32_kernel(
    const unsigned short* __restrict__ A, const unsigned short* __restrict__ W,
    const float* __restrict__ bias, float* __restrict__ out) {
  const int tid = threadIdx.x;
  const int bm = blockIdx.x / (C_DIM / OBN);
  const int bn = blockIdx.x % (C_DIM / OBN);
  f32x4 acc[2][2] = {};
  gemm_body_64x64(A, W, acc, bm, bn, tid);
  const int w = tid >> 6, lane = tid & 63;
  const int quad = lane >> 4, r = lane & 15;
  const int wm = (w >> 1) * 32, wn = (w & 1) * 32;
  #pragma unroll
  for (int mi = 0; mi < 2; ++mi) {
    #pragma unroll
    for (int ni = 0; ni < 2; ++ni) {
      const int col = bn * OBN + wn + ni * 16 + r;
      const float bf = bias[col];
      #pragma unroll
      for (int i = 0; i < 4; ++i) {
        const int row = bm * OBM + wm + mi * 16 + quad * 4 + i;
        out[(size_t)row * C_DIM + col] = acc[mi][ni][i] + bf;
      }
    }
  }
}

// ---- launch 3: per-t top-64 selection table (one wave per t).
// Stores RAW row indices into sel[t][64]. ----
__global__ __launch_bounds__(256) void select_kernel(
    const int* __restrict__ sorted_idx, int* __restrict__ sel) {
  const int tid = threadIdx.x;
  const int w = tid >> 6, lane = tid & 63;
  const int t = blockIdx.x * 4 + w;
  int* dst = sel + (size_t)t * KSP;
  if (t <= 63) {
    // positions 0..t-1 once, index t duplicated for the remainder — same
    // multiset as the reference's min(top_k_idx, t) clamp on -inf entries.
    dst[lane] = (lane < t) ? lane : t;
    return;
  }
  const unsigned long long lt_mask = (1ull << lane) - 1ull;
  int count = 0;
  for (int chunk = 0; chunk < T_DIM / 64 && count < KSP; ++chunk) {
    int s = sorted_idx[chunk * 64 + lane];
    s = (s < 0) ? 0 : (s > T_DIM - 1 ? T_DIM - 1 : s);
    const bool ok = (s <= t);
    const unsigned long long mm = __ballot(ok);
    const int pos = count + __popcll(mm & lt_mask);
    if (ok && pos < KSP) dst[pos] = s;
    count += __popcll(mm);
  }
}

// ---- launch 4: union-tiled sparse attention.
// Block = (32 consecutive t's, one head). Builds the union row-set of the 32
// selections via an LDS map + ballot scan (<= 95 rows), gathers each unique
// K/V head-slice ONCE into LDS (padded stride 144B), then each wave computes
// 8 t's entirely out of LDS. Global gather traffic: 512 MB -> ~24 MB. ----
__global__ __launch_bounds__(256) void attn_kernel(
    const unsigned short* __restrict__ q, const unsigned short* __restrict__ k,
    const unsigned short* __restrict__ v, const int* __restrict__ sel,
    unsigned short* __restrict__ attn_out) {
  __shared__ unsigned short Kl[USLOT * KSTR];   // 13.5 KB
  __shared__ unsigned short Vl[USLOT * KSTR];   // 13.5 KB
  __shared__ short map_s[T_DIM];                // 4 KB  row -> slot (or -1/1)
  __shared__ short slots_tab[ATB][KSP];         // 4 KB  per-t slot lists
  __shared__ short urows[USLOT];
  __shared__ int Ucnt;
  const int tb = blockIdx.x >> 4;       // / NH
  const int h = blockIdx.x & (NH - 1);
  const int t0 = tb * ATB;
  const int tid = threadIdx.x;
  const int w = tid >> 6, lane = tid & 63;
  // 1. init map
  #pragma unroll
  for (int i = 0; i < T_DIM / 256; ++i) map_s[tid + i * 256] = -1;
  __syncthreads();
  // 2. mark all selected rows (duplicate stores of 1 are benign)
  int rowreg[ATB * KSP / 256];  // 8 entries/thread, reused in step 4a
  #pragma unroll
  for (int i = 0; i < ATB * KSP / 256; ++i) {
    rowreg[i] = sel[(size_t)t0 * KSP + tid + i * 256];
    map_s[rowreg[i]] = 1;
  }
  __syncthreads();
  // 3. wave 0: assign slots in row order, record unique rows
  if (w == 0) {
    const unsigned long long lt_mask = (1ull << lane) - 1ull;
    int count = 0;
    const int nch = (t0 + ATB + 63) >> 6;
    for (int c = 0; c < nch; ++c) {
      const int rowi = c * 64 + lane;
      const bool ok = (map_s[rowi] == 1);
      const unsigned long long mm = __ballot(ok);
      const int pos = count + __popcll(mm & lt_mask);
      if (ok) { map_s[rowi] = (short)pos; urows[pos] = (short)rowi; }
      count += __popcll(mm);
    }
    if (lane == 0) Ucnt = count;
  }
  __syncthreads();
  // 4a. per-t slot tables (map now holds slot ids)
  #pragma unroll
  for (int i = 0; i < ATB * KSP / 256; ++i)
    (&slots_tab[0][0])[tid + i * 256] = map_s[rowreg[i]];
  // 4b. gather unique K/V head-slices into LDS (128B per row, 8 lanes/row)
  {
    const int U = Ucnt;
    const int e8 = tid & 7;
    for (int s = tid >> 3; s < U; s += 32) {
      const int row = urows[s];
      const size_t gb = (size_t)row * C_DIM + h * HS + e8 * 8;
      *reinterpret_cast<uint4*>(&Kl[s * KSTR + e8 * 8]) =
          *reinterpret_cast<const uint4*>(k + gb);
      *reinterpret_cast<uint4*>(&Vl[s * KSTR + e8 * 8]) =
          *reinterpret_cast<const uint4*>(v + gb);
    }
  }
  __syncthreads();
  // 5. compute: wave w handles t = t0 + w*8 + i, all data from LDS
  const int c8 = lane & 7;
  const int ksub = lane >> 3;
  for (int i = 0; i < ATB / 4; ++i) {
    const int tt = w * (ATB / 4) + i;
    const int t = t0 + tt;
    const uint4 qraw =
        *reinterpret_cast<const uint4*>(q + (size_t)t * C_DIM + h * HS + 8 * c8);
    int slot[8];
    #pragma unroll
    for (int jj = 0; jj < 8; ++jj) slot[jj] = slots_tab[tt][8 * jj + ksub];
    // phase 1: logits via f16 dot2 from LDS K
    float l[8];
    #pragma unroll
    for (int jj = 0; jj < 8; ++jj) {
      const uint4 raw =
          *reinterpret_cast<const uint4*>(&Kl[slot[jj] * KSTR + 8 * c8]);
      float pl = dot2h(raw.x, qraw.x, 0.f);
      pl = dot2h(raw.y, qraw.y, pl);
      pl = dot2h(raw.z, qraw.z, pl);
      pl = dot2h(raw.w, qraw.w, pl);
      pl *= 0.125f;
      pl += __shfl_xor(pl, 1);
      pl += __shfl_xor(pl, 2);
      pl += __shfl_xor(pl, 4);
      l[jj] = pl;
    }
    float m = l[0];
    #pragma unroll
    for (int jj = 1; jj < 8; ++jj) m = fmaxf(m, l[jj]);
    m = fmaxf(m, __shfl_xor(m, 8));
    m = fmaxf(m, __shfl_xor(m, 16));
    m = fmaxf(m, __shfl_xor(m, 32));
    float sum = 0.f;
    #pragma unroll
    for (int jj = 0; jj < 8; ++jj) {
      l[jj] = __expf(l[jj] - m);
      sum += l[jj];
    }
    sum += __shfl_xor(sum, 8);
    sum += __shfl_xor(sum, 16);
    sum += __shfl_xor(sum, 32);
    const float rs = 1.0f / sum;
    // phase 2: weighted V (bf16) sum from LDS V
    float a[8] = {0.f, 0.f, 0.f, 0.f, 0.f, 0.f, 0.f, 0.f};
    #pragma unroll
    for (int jj = 0; jj < 8; ++jj) {
      const uint4 raw =
          *reinterpret_cast<const uint4*>(&Vl[slot[jj] * KSTR + 8 * c8]);
      const float p = l[jj] * rs;
      a[0] += p * bflo(raw.x); a[1] += p * bfhi(raw.x);
      a[2] += p * bflo(raw.y); a[3] += p * bfhi(raw.y);
      a[4] += p * bflo(raw.z); a[5] += p * bfhi(raw.z);
      a[6] += p * bflo(raw.w); a[7] += p * bfhi(raw.w);
    }
    #pragma unroll
    for (int o = 8; o <= 32; o <<= 1) {
      #pragma unroll
      for (int z = 0; z < 8; ++z) a[z] += __shfl_xor(a[z], o);
    }
    if (ksub == 0) {
      ushort4 o0, o1;
      o0.x = f2bfu(a[0]); o0.y = f2bfu(a[1]); o0.z = f2bfu(a[2]); o0.w = f2bfu(a[3]);
      o1.x = f2bfu(a[4]); o1.y = f2bfu(a[5]); o1.z = f2bfu(a[6]); o1.w = f2bfu(a[7]);
      ushort4* dst =
          reinterpret_cast<ushort4*>(attn_out + (size_t)t * C_DIM + h * HS + 8 * c8);
      dst[0] = o0;
      dst[1] = o1;
    }
  }
}

extern "C" void kernel_launch(void* const* d_in, const int* in_sizes, int n_in,
                              void* d_out, int out_size, void* d_ws, size_t ws_size,
                              hipStream_t stream) {
  const float* x   = (const float*)d_in[0];
  const float* Wq  = (const float*)d_in[1];
  const float* bq  = (const float*)d_in[2];
  const float* Wk  = (const float*)d_in[3];
  const float* bk  = (const float*)d_in[4];
  const float* Wv  = (const float*)d_in[5];
  const float* bv  = (const float*)d_in[6];
  const float* Wo  = (const float*)d_in[7];
  const float* bo  = (const float*)d_in[8];
  const float* Wks = (const float*)d_in[9];
  const float* bks = (const float*)d_in[10];
  float* out = (float*)d_out;

  char* ws = (char*)d_ws;
  size_t off = 0;
  float* scores = (float*)(ws + off); off += 8192;
  int*   sorted = (int*)(ws + off);   off += 8192;
  int*   sel    = (int*)(ws + off);   off += (size_t)T_DIM * KSP * 4;  // 512 KB
  unsigned short* xb  = (unsigned short*)(ws + off); off += (size_t)T_DIM * C_DIM * 2;
  unsigned short* Wqb = (unsigned short*)(ws + off); off += (size_t)C_DIM * C_DIM * 2;
  unsigned short* Wkb = (unsigned short*)(ws + off); off += (size_t)C_DIM * C_DIM * 2;
  unsigned short* Wvb = (unsigned short*)(ws + off); off += (size_t)C_DIM * C_DIM * 2;
  unsigned short* Wob = (unsigned short*)(ws + off); off += (size_t)C_DIM * C_DIM * 2;
  unsigned short* qb  = (unsigned short*)(ws + off); off += (size_t)T_DIM * C_DIM * 2;
  unsigned short* kb  = (unsigned short*)(ws + off); off += (size_t)T_DIM * C_DIM * 2;
  unsigned short* vb  = (unsigned short*)(ws + off); off += (size_t)T_DIM * C_DIM * 2;
  unsigned short* ab  = xb;  // alias: xb dead after gemm_qkv

  // launch 1: conversion + scores
  convert_scores_kernel<<<NSCORE + NCONV, 256, 0, stream>>>(
      x, Wq, Wk, Wv, Wo, Wks, bks, xb, Wqb, Wkb, Wvb, Wob, scores);

  // launch 2: rank-sort (512 blocks) + fused QKV GEMM (768 blocks)
  gemm_qkv_rank_kernel<<<NRANK + 3 * (T_DIM / GBM) * (C_DIM / GBN), 256, 0,
                         stream>>>(
      xb, Wqb, Wkb, Wvb, bq, bk, bv, qb, kb, vb, scores, sorted);

  // launch 3: per-t top-64 selection table (one wave per t, raw indices)
  select_kernel<<<T_DIM / 4, 256, 0, stream>>>(sorted, sel);

  // launch 4: union-tiled attention (64 t-blocks x 16 heads)
  attn_kernel<<<(T_DIM / ATB) * NH, 256, 0, stream>>>(qb, kb, vb, sel, ab);

  // launch 5: output projection
  gemm_o_f32_kernel<<<(T_DIM / OBM) * (C_DIM / OBN), 256, 0, stream>>>(
      ab, Wob, bo, out);
}

// Round 3
// 160.899 us; speedup vs baseline: 1.0618x; 1.0618x over previous
//
#include <hip/hip_runtime.h>
#include <hip/hip_bf16.h>
#include <cstdint>
#include <cstddef>

#define T_DIM 2048
#define C_DIM 1024
#define NH 16
#define HS 64
#define KSP 64

// QKV GEMM: 128x64 tile, BK=128, XOR-swizzled LDS, global_load_lds staging
#define GBM 128
#define GBN 64
#define GBK 128
// o-proj GEMM: 64x64 tile (512 blocks = 2/CU)
#define OBM 64
#define OBN 64

// attention tiling: ATB consecutive t's per block, one head per block.
// union(tile) = sel(t0) UNION {t0+1..t0+ATB-1}  (prefix property), so slots
// are assigned positionally — no scan, no map init. KSTR=66 shorts (132B)
// gives LDS bank stride 33===1 (mod 32): read banks (slot + 4*c8)%32, ~2-way.
#define ATB 16
#define USLOT (KSP + ATB - 1)  // 79
#define KSTR 66

typedef short short8 __attribute__((ext_vector_type(8)));
typedef float f32x4 __attribute__((ext_vector_type(4)));
typedef _Float16 half2_t __attribute__((ext_vector_type(2)));

__device__ __forceinline__ unsigned short f2bfu(float f) {
  unsigned u = __builtin_bit_cast(unsigned, f);
  unsigned r = (u + 0x7fffu + ((u >> 16) & 1u)) >> 16;
  return (unsigned short)r;
}
__device__ __forceinline__ unsigned short f2h(float f) {
  _Float16 h = (_Float16)f;
  return __builtin_bit_cast(unsigned short, h);
}
__device__ __forceinline__ float bflo(unsigned u) {
  return __builtin_bit_cast(float, u << 16);
}
__device__ __forceinline__ float bfhi(unsigned u) {
  return __builtin_bit_cast(float, u & 0xffff0000u);
}

__device__ __forceinline__ float dot2h(unsigned kbits, unsigned qbits, float acc) {
#if __has_builtin(__builtin_amdgcn_fdot2)
  return __builtin_amdgcn_fdot2(__builtin_bit_cast(half2_t, kbits),
                                __builtin_bit_cast(half2_t, qbits), acc, false);
#else
  half2_t kk = __builtin_bit_cast(half2_t, kbits);
  half2_t qq = __builtin_bit_cast(half2_t, qbits);
  return acc + (float)kk.x * (float)qq.x + (float)kk.y * (float)qq.y;
#endif
}

#define GLOAD_LDS16(gp, lp)                                                  \
  __builtin_amdgcn_global_load_lds(                                          \
      (const __attribute__((address_space(1))) void*)(gp),                   \
      (__attribute__((address_space(3))) void*)(lp), 16, 0, 0)

// ---- launch 1: key_scores (blocks [0,512)) + f32->bf16 conversion (rest) ----
#define NSCORE (T_DIM / 4)  // 512
#define NCONV ((T_DIM * C_DIM + 4 * C_DIM * C_DIM) / 4 / 256)  // 6144
__global__ __launch_bounds__(256) void convert_scores_kernel(
    const float* __restrict__ x, const float* __restrict__ Wq,
    const float* __restrict__ Wk, const float* __restrict__ Wv,
    const float* __restrict__ Wo, const float* __restrict__ Wks,
    const float* __restrict__ bks,
    unsigned short* __restrict__ xb, unsigned short* __restrict__ Wqb,
    unsigned short* __restrict__ Wkb, unsigned short* __restrict__ Wvb,
    unsigned short* __restrict__ Wob, float* __restrict__ scores) {
  if (blockIdx.x < NSCORE) {
    const int t = blockIdx.x * 4 + (threadIdx.x >> 6);
    const int lane = threadIdx.x & 63;
    const float* xrow = x + (size_t)t * C_DIM;
    float acc = 0.f;
    #pragma unroll 4
    for (int i = lane; i < C_DIM; i += 64)
      acc += xrow[i] * Wks[i];
    #pragma unroll
    for (int o = 32; o; o >>= 1) acc += __shfl_xor(acc, o);
    if (lane == 0) scores[t] = acc + bks[0];
    return;
  }
  const int i = (blockIdx.x - NSCORE) * 256 + threadIdx.x;
  const int NX4 = T_DIM * C_DIM / 4;
  const int NW4 = C_DIM * C_DIM / 4;
  const float* src;
  unsigned short* dst;
  int j = i;
  if (j < NX4) { src = x; dst = xb; }
  else {
    j -= NX4;
    int w = j / NW4;
    j -= w * NW4;
    src = (w == 0) ? Wq : (w == 1) ? Wk : (w == 2) ? Wv : Wo;
    dst = (w == 0) ? Wqb : (w == 1) ? Wkb : (w == 2) ? Wvb : Wob;
  }
  float4 f = reinterpret_cast<const float4*>(src)[j];
  ushort4 o;
  o.x = f2bfu(f.x); o.y = f2bfu(f.y); o.z = f2bfu(f.z); o.w = f2bfu(f.w);
  reinterpret_cast<ushort4*>(dst)[j] = o;
}

// ---- GEMM body: 128x64 tile, BK=128; LDS passed in (shared arena) ----
__device__ __forceinline__ void gemm_body_128x64(
    const unsigned short* __restrict__ A, const unsigned short* __restrict__ W,
    f32x4 acc[4][2], int bm, int bn, int tid,
    unsigned short* As, unsigned short* Ws) {
  const int w = tid >> 6, lane = tid & 63;
  const int quad = lane >> 4, r = lane & 15;
  const int wm = (w >> 1) * 64, wn = (w & 1) * 32;
  const int sub = lane >> 4;
  const int c = lane & 15;
  const unsigned short* Arow[8];
  const unsigned short* Wrow[4];
  #pragma unroll
  for (int i = 0; i < 8; ++i) {
    const int row = w * 32 + i * 4 + sub;
    Arow[i] = A + (size_t)(bm * GBM + row) * C_DIM + ((c ^ (row & 7)) * 8);
  }
  #pragma unroll
  for (int i = 0; i < 4; ++i) {
    const int row = w * 16 + i * 4 + sub;
    Wrow[i] = W + (size_t)(bn * GBN + row) * C_DIM + ((c ^ (row & 7)) * 8);
  }
  for (int kb = 0; kb < C_DIM; kb += GBK) {
    #pragma unroll
    for (int i = 0; i < 8; ++i)
      GLOAD_LDS16(Arow[i] + kb, &As[(w * 32 + i * 4) * GBK]);
    #pragma unroll
    for (int i = 0; i < 4; ++i)
      GLOAD_LDS16(Wrow[i] + kb, &Ws[(w * 16 + i * 4) * GBK]);
    __syncthreads();
    #pragma unroll
    for (int ks = 0; ks < 4; ++ks) {
      const int pc = ((ks * 4 + quad) ^ (r & 7)) * 8;
      short8 af[4], bfr[2];
      #pragma unroll
      for (int mi = 0; mi < 4; ++mi)
        af[mi] = *reinterpret_cast<const short8*>(&As[(wm + mi * 16 + r) * GBK + pc]);
      #pragma unroll
      for (int ni = 0; ni < 2; ++ni)
        bfr[ni] = *reinterpret_cast<const short8*>(&Ws[(wn + ni * 16 + r) * GBK + pc]);
      #pragma unroll
      for (int mi = 0; mi < 4; ++mi)
        #pragma unroll
        for (int ni = 0; ni < 2; ++ni)
          acc[mi][ni] = __builtin_amdgcn_mfma_f32_16x16x32_bf16(af[mi], bfr[ni], acc[mi][ni], 0, 0, 0);
    }
    __syncthreads();
  }
}

// ---- launch 2: rank_sort (blocks [0,512)) + fused QKV GEMM (rest). ----
#define NRANK (T_DIM / 4)  // 512
__global__ __launch_bounds__(256) void gemm_qkv_rank_kernel(
    const unsigned short* __restrict__ A,
    const unsigned short* __restrict__ Wq, const unsigned short* __restrict__ Wk,
    const unsigned short* __restrict__ Wv,
    const float* __restrict__ bq, const float* __restrict__ bk,
    const float* __restrict__ bv,
    unsigned short* __restrict__ qo, unsigned short* __restrict__ ko,
    unsigned short* __restrict__ vo,
    const float* __restrict__ scores, int* __restrict__ sorted_idx) {
  __shared__ unsigned short lds[(GBM + GBN) * GBK];  // 48 KB arena
  const int tid = threadIdx.x;
  if (blockIdx.x < NRANK) {
    // rank-by-counting sort: one wave per element, lane-parallel scan
    float* ss = reinterpret_cast<float*>(lds);  // first 8 KB of arena
    for (int j = tid; j < T_DIM; j += 256) ss[j] = scores[j];
    __syncthreads();
    const int w = tid >> 6, lane = tid & 63;
    const int i = blockIdx.x * 4 + w;
    const float si = ss[i];
    int rank = 0;
    #pragma unroll
    for (int step = 0; step < T_DIM / 64; ++step) {
      const int j = step * 64 + lane;
      const float sj = ss[j];
      rank += (int)((sj > si) || (sj == si && j < i));
    }
    #pragma unroll
    for (int o = 32; o; o >>= 1) rank += __shfl_xor(rank, o);
    if (lane == 0) sorted_idx[rank] = i;
    return;
  }
  const int bid = blockIdx.x - NRANK;
  const int per = (T_DIM / GBM) * (C_DIM / GBN);  // 256
  const int which = bid / per;
  const int rem = bid % per;
  const int bm = rem / (C_DIM / GBN);
  const int bn = rem % (C_DIM / GBN);
  const unsigned short* W = (which == 0) ? Wq : (which == 1) ? Wk : Wv;
  const float* bias = (which == 0) ? bq : (which == 1) ? bk : bv;
  unsigned short* out = (which == 0) ? qo : (which == 1) ? ko : vo;
  f32x4 acc[4][2] = {};
  gemm_body_128x64(A, W, acc, bm, bn, tid, lds, lds + GBM * GBK);
  const int w = tid >> 6, lane = tid & 63;
  const int quad = lane >> 4, r = lane & 15;
  const int wm = (w >> 1) * 64, wn = (w & 1) * 32;
  #pragma unroll
  for (int mi = 0; mi < 4; ++mi) {
    #pragma unroll
    for (int ni = 0; ni < 2; ++ni) {
      const int col = bn * GBN + wn + ni * 16 + r;
      const float bf = bias[col];
      #pragma unroll
      for (int i = 0; i < 4; ++i) {
        const int row = bm * GBM + wm + mi * 16 + quad * 4 + i;
        const float val = acc[mi][ni][i] + bf;
        // q,k -> f16 (fdot2 path in attn); v -> bf16
        out[(size_t)row * C_DIM + col] = (which == 2) ? f2bfu(val) : f2h(val);
      }
    }
  }
}

// ---- o-proj GEMM body: 64x64 tile, BK=128 ----
__device__ __forceinline__ void gemm_body_64x64(
    const unsigned short* __restrict__ A, const unsigned short* __restrict__ W,
    f32x4 acc[2][2], int bm, int bn, int tid) {
  __shared__ unsigned short As[OBM * GBK];  // 16 KB
  __shared__ unsigned short Ws[OBN * GBK];  // 16 KB
  const int w = tid >> 6, lane = tid & 63;
  const int quad = lane >> 4, r = lane & 15;
  const int wm = (w >> 1) * 32, wn = (w & 1) * 32;
  const int sub = lane >> 4;
  const int c = lane & 15;
  const unsigned short* Arow[4];
  const unsigned short* Wrow[4];
  #pragma unroll
  for (int i = 0; i < 4; ++i) {
    const int row = w * 16 + i * 4 + sub;
    Arow[i] = A + (size_t)(bm * OBM + row) * C_DIM + ((c ^ (row & 7)) * 8);
    Wrow[i] = W + (size_t)(bn * OBN + row) * C_DIM + ((c ^ (row & 7)) * 8);
  }
  for (int kb = 0; kb < C_DIM; kb += GBK) {
    #pragma unroll
    for (int i = 0; i < 4; ++i)
      GLOAD_LDS16(Arow[i] + kb, &As[(w * 16 + i * 4) * GBK]);
    #pragma unroll
    for (int i = 0; i < 4; ++i)
      GLOAD_LDS16(Wrow[i] + kb, &Ws[(w * 16 + i * 4) * GBK]);
    __syncthreads();
    #pragma unroll
    for (int ks = 0; ks < 4; ++ks) {
      const int pc = ((ks * 4 + quad) ^ (r & 7)) * 8;
      short8 af[2], bfr[2];
      #pragma unroll
      for (int mi = 0; mi < 2; ++mi)
        af[mi] = *reinterpret_cast<const short8*>(&As[(wm + mi * 16 + r) * GBK + pc]);
      #pragma unroll
      for (int ni = 0; ni < 2; ++ni)
        bfr[ni] = *reinterpret_cast<const short8*>(&Ws[(wn + ni * 16 + r) * GBK + pc]);
      #pragma unroll
      for (int mi = 0; mi < 2; ++mi)
        #pragma unroll
        for (int ni = 0; ni < 2; ++ni)
          acc[mi][ni] = __builtin_amdgcn_mfma_f32_16x16x32_bf16(af[mi], bfr[ni], acc[mi][ni], 0, 0, 0);
    }
    __syncthreads();
  }
}

// ---- launch 4: output projection GEMM, fp32 out, 64x64 tile ----
__global__ __launch_bounds__(256) void gemm_o_f32_kernel(
    const unsigned short* __restrict__ A, const unsigned short* __restrict__ W,
    const float* __restrict__ bias, float* __restrict__ out) {
  const int tid = threadIdx.x;
  const int bm = blockIdx.x / (C_DIM / OBN);
  const int bn = blockIdx.x % (C_DIM / OBN);
  f32x4 acc[2][2] = {};
  gemm_body_64x64(A, W, acc, bm, bn, tid);
  const int w = tid >> 6, lane = tid & 63;
  const int quad = lane >> 4, r = lane & 15;
  const int wm = (w >> 1) * 32, wn = (w & 1) * 32;
  #pragma unroll
  for (int mi = 0; mi < 2; ++mi) {
    #pragma unroll
    for (int ni = 0; ni < 2; ++ni) {
      const int col = bn * OBN + wn + ni * 16 + r;
      const float bf = bias[col];
      #pragma unroll
      for (int i = 0; i < 4; ++i) {
        const int row = bm * OBM + wm + mi * 16 + quad * 4 + i;
        out[(size_t)row * C_DIM + col] = acc[mi][ni][i] + bf;
      }
    }
  }
}

// ---- launch 3: union-tiled sparse attention v3.
// Block = (16 consecutive t's, one head); 2048 blocks, 4 waves, 4 t's/wave.
// Union slots assigned POSITIONALLY (no scan/init): slot j<64 = sel(t0)[j],
// slots 64..78 = rows t0+1..t0+15. Per-t selections via early-exit ballot
// scan of `sorted` (avg ~4 chunks). K/V union gathered once to LDS
// (KSTR=66 -> bank stride 1). Gather traffic 512 MB -> ~45 MB. ----
__global__ __launch_bounds__(256) void attn_kernel(
    const unsigned short* __restrict__ q, const unsigned short* __restrict__ k,
    const unsigned short* __restrict__ v, const int* __restrict__ sorted_idx,
    unsigned short* __restrict__ attn_out) {
  __shared__ unsigned short Kl[USLOT * KSTR];  // 79*66*2 = 10428 B
  __shared__ unsigned short Vl[USLOT * KSTR];  // 10428 B
  __shared__ short map_s[T_DIM];               // 4 KB; only union entries written
  __shared__ short rows_tab[ATB][KSP];         // 2 KB
  __shared__ short urows[USLOT];
  const int tb = blockIdx.x >> 4;
  const int h = blockIdx.x & (NH - 1);
  const int t0 = tb * ATB;
  const int tid = threadIdx.x;
  const int w = tid >> 6, lane = tid & 63;
  const int c8 = lane & 7;
  const int ksub = lane >> 3;
  // hoist Q loads (independent of all LDS phases)
  uint4 qr[ATB / 4];
  #pragma unroll
  for (int li = 0; li < ATB / 4; ++li) {
    const int t = t0 + w * (ATB / 4) + li;
    qr[li] = *reinterpret_cast<const uint4*>(q + (size_t)t * C_DIM + h * HS + 8 * c8);
  }
  // phase A: per-wave selection scans (4 t's each); wave0's t0 seeds union
  const unsigned long long lt_mask = (1ull << lane) - 1ull;
  for (int li = 0; li < ATB / 4; ++li) {
    const int tt = w * (ATB / 4) + li;
    const int t = t0 + tt;
    if (t <= 63) {
      // reference semantics: rows 0..t-1 once, row t duplicated (clamped -inf picks)
      rows_tab[tt][lane] = (short)((lane < t) ? lane : t);
    } else {
      int count = 0;
      for (int c = 0; c < T_DIM / 64 && count < KSP; ++c) {
        int s = sorted_idx[c * 64 + lane];
        s = (s < 0) ? 0 : (s > T_DIM - 1 ? T_DIM - 1 : s);
        const bool ok = (s <= t);
        const unsigned long long mm = __ballot(ok);
        const int pos = count + __popcll(mm & lt_mask);
        if (ok && pos < KSP) rows_tab[tt][pos] = (short)s;
        count += __popcll(mm);
      }
    }
    if (w == 0 && li == 0) {
      // union = sel(t0) U {t0+1..t0+ATB-1}; positional slots.
      // dup rows (t0<64) race-write map_s — benign: all winning slots hold
      // identical row data.
      const int r0 = rows_tab[0][lane];
      map_s[r0] = (short)lane;
      urows[lane] = (short)r0;
      if (lane < ATB - 1) {
        map_s[t0 + 1 + lane] = (short)(KSP + lane);
        urows[KSP + lane] = (short)(t0 + 1 + lane);
      }
    }
  }
  __syncthreads();
  // phase B: gather union K/V head slices into LDS (8 lanes per row)
  {
    const int e8 = tid & 7;
    for (int s = tid >> 3; s < USLOT; s += 32) {
      const int row = urows[s];
      const size_t gb = (size_t)row * C_DIM + h * HS + e8 * 8;
      *reinterpret_cast<uint4*>(&Kl[s * KSTR + e8 * 8]) =
          *reinterpret_cast<const uint4*>(k + gb);
      *reinterpret_cast<uint4*>(&Vl[s * KSTR + e8 * 8]) =
          *reinterpret_cast<const uint4*>(v + gb);
    }
  }
  __syncthreads();
  // phase C: compute 4 t's per wave, all K/V from LDS
  for (int li = 0; li < ATB / 4; ++li) {
    const int tt = w * (ATB / 4) + li;
    const int t = t0 + tt;
    const uint4 qraw = qr[li];
    int slot[8];
    #pragma unroll
    for (int jj = 0; jj < 8; ++jj)
      slot[jj] = map_s[rows_tab[tt][8 * jj + ksub]];
    // phase 1: logits via f16 dot2 from LDS K
    float l[8];
    #pragma unroll
    for (int jj = 0; jj < 8; ++jj) {
      const uint4 raw =
          *reinterpret_cast<const uint4*>(&Kl[slot[jj] * KSTR + 8 * c8]);
      float pl = dot2h(raw.x, qraw.x, 0.f);
      pl = dot2h(raw.y, qraw.y, pl);
      pl = dot2h(raw.z, qraw.z, pl);
      pl = dot2h(raw.w, qraw.w, pl);
      pl *= 0.125f;
      pl += __shfl_xor(pl, 1);
      pl += __shfl_xor(pl, 2);
      pl += __shfl_xor(pl, 4);
      l[jj] = pl;
    }
    float m = l[0];
    #pragma unroll
    for (int jj = 1; jj < 8; ++jj) m = fmaxf(m, l[jj]);
    m = fmaxf(m, __shfl_xor(m, 8));
    m = fmaxf(m, __shfl_xor(m, 16));
    m = fmaxf(m, __shfl_xor(m, 32));
    float sum = 0.f;
    #pragma unroll
    for (int jj = 0; jj < 8; ++jj) {
      l[jj] = __expf(l[jj] - m);
      sum += l[jj];
    }
    sum += __shfl_xor(sum, 8);
    sum += __shfl_xor(sum, 16);
    sum += __shfl_xor(sum, 32);
    const float rs = 1.0f / sum;
    // phase 2: weighted V (bf16) sum from LDS V
    float a[8] = {0.f, 0.f, 0.f, 0.f, 0.f, 0.f, 0.f, 0.f};
    #pragma unroll
    for (int jj = 0; jj < 8; ++jj) {
      const uint4 raw =
          *reinterpret_cast<const uint4*>(&Vl[slot[jj] * KSTR + 8 * c8]);
      const float p = l[jj] * rs;
      a[0] += p * bflo(raw.x); a[1] += p * bfhi(raw.x);
      a[2] += p * bflo(raw.y); a[3] += p * bfhi(raw.y);
      a[4] += p * bflo(raw.z); a[5] += p * bfhi(raw.z);
      a[6] += p * bflo(raw.w); a[7] += p * bfhi(raw.w);
    }
    #pragma unroll
    for (int o = 8; o <= 32; o <<= 1) {
      #pragma unroll
      for (int z = 0; z < 8; ++z) a[z] += __shfl_xor(a[z], o);
    }
    if (ksub == 0) {
      ushort4 o0, o1;
      o0.x = f2bfu(a[0]); o0.y = f2bfu(a[1]); o0.z = f2bfu(a[2]); o0.w = f2bfu(a[3]);
      o1.x = f2bfu(a[4]); o1.y = f2bfu(a[5]); o1.z = f2bfu(a[6]); o1.w = f2bfu(a[7]);
      ushort4* dst =
          reinterpret_cast<ushort4*>(attn_out + (size_t)t * C_DIM + h * HS + 8 * c8);
      dst[0] = o0;
      dst[1] = o1;
    }
  }
}

extern "C" void kernel_launch(void* const* d_in, const int* in_sizes, int n_in,
                              void* d_out, int out_size, void* d_ws, size_t ws_size,
                              hipStream_t stream) {
  const float* x   = (const float*)d_in[0];
  const float* Wq  = (const float*)d_in[1];
  const float* bq  = (const float*)d_in[2];
  const float* Wk  = (const float*)d_in[3];
  const float* bk  = (const float*)d_in[4];
  const float* Wv  = (const float*)d_in[5];
  const float* bv  = (const float*)d_in[6];
  const float* Wo  = (const float*)d_in[7];
  const float* bo  = (const float*)d_in[8];
  const float* Wks = (const float*)d_in[9];
  const float* bks = (const float*)d_in[10];
  float* out = (float*)d_out;

  char* ws = (char*)d_ws;
  size_t off = 0;
  float* scores = (float*)(ws + off); off += 8192;
  int*   sorted = (int*)(ws + off);   off += 8192;
  unsigned short* xb  = (unsigned short*)(ws + off); off += (size_t)T_DIM * C_DIM * 2;
  unsigned short* Wqb = (unsigned short*)(ws + off); off += (size_t)C_DIM * C_DIM * 2;
  unsigned short* Wkb = (unsigned short*)(ws + off); off += (size_t)C_DIM * C_DIM * 2;
  unsigned short* Wvb = (unsigned short*)(ws + off); off += (size_t)C_DIM * C_DIM * 2;
  unsigned short* Wob = (unsigned short*)(ws + off); off += (size_t)C_DIM * C_DIM * 2;
  unsigned short* qb  = (unsigned short*)(ws + off); off += (size_t)T_DIM * C_DIM * 2;
  unsigned short* kb  = (unsigned short*)(ws + off); off += (size_t)T_DIM * C_DIM * 2;
  unsigned short* vb  = (unsigned short*)(ws + off); off += (size_t)T_DIM * C_DIM * 2;
  unsigned short* ab  = xb;  // alias: xb dead after gemm_qkv

  // launch 1: conversion + scores
  convert_scores_kernel<<<NSCORE + NCONV, 256, 0, stream>>>(
      x, Wq, Wk, Wv, Wo, Wks, bks, xb, Wqb, Wkb, Wvb, Wob, scores);

  // launch 2: rank-sort (512 blocks) + fused QKV GEMM (768 blocks)
  gemm_qkv_rank_kernel<<<NRANK + 3 * (T_DIM / GBM) * (C_DIM / GBN), 256, 0,
                         stream>>>(
      xb, Wqb, Wkb, Wvb, bq, bk, bv, qb, kb, vb, scores, sorted);

  // launch 3: union-tiled attention (128 t-tiles x 16 heads = 2048 blocks)
  attn_kernel<<<(T_DIM / ATB) * NH, 256, 0, stream>>>(qb, kb, vb, sorted, ab);

  // launch 4: output projection
  gemm_o_f32_kernel<<<(T_DIM / OBM) * (C_DIM / OBN), 256, 0, stream>>>(
      ab, Wob, bo, out);
}

// Round 5
// 160.789 us; speedup vs baseline: 1.0625x; 1.0007x over previous
//
#include <hip/hip_runtime.h>
#include <hip/hip_bf16.h>
#include <cstdint>
#include <cstddef>

#define T_DIM 2048
#define C_DIM 1024
#define NH 16
#define HS 64
#define KSP 64

// QKV GEMM: 128x64 tile, BK=128, XOR-swizzled LDS, global_load_lds staging
#define GBM 128
#define GBN 64
#define GBK 128
// o-proj GEMM: 64x64 tile (512 blocks = 2/CU)
#define OBM 64
#define OBN 64

// attention tiling: ATB consecutive t's per block, one head per block.
// union(tile) = sel(t0) UNION {t0+1..t0+ATB-1} (prefix property) -> slots
// positional. KSTR=66 shorts (132B): bank stride 33===1 mod 32, ~2-way.
#define ATB 16
#define USLOT (KSP + ATB - 1)  // 79
#define KSTR 66

// DPP controls (lane-permute on VALU pipe, replaces ds_swizzle shuffles)
#define DPP_XOR1 0xB1        // quad_perm(1,0,3,2)
#define DPP_XOR2 0x4E        // quad_perm(2,3,0,1)
#define DPP_HMIRR 0x141      // row_half_mirror: i -> i^7 within 8 (xor4 after xor1,2)
#define DPP_ROR8 0x128       // row_ror:8: i -> i^8 within 16

typedef short short8 __attribute__((ext_vector_type(8)));
typedef float f32x4 __attribute__((ext_vector_type(4)));
typedef _Float16 half2_t __attribute__((ext_vector_type(2)));

__device__ __forceinline__ unsigned short f2bfu(float f) {
  unsigned u = __builtin_bit_cast(unsigned, f);
  unsigned r = (u + 0x7fffu + ((u >> 16) & 1u)) >> 16;
  return (unsigned short)r;
}
__device__ __forceinline__ unsigned short f2h(float f) {
  _Float16 h = (_Float16)f;
  return __builtin_bit_cast(unsigned short, h);
}
__device__ __forceinline__ float bflo(unsigned u) {
  return __builtin_bit_cast(float, u << 16);
}
__device__ __forceinline__ float bfhi(unsigned u) {
  return __builtin_bit_cast(float, u & 0xffff0000u);
}

// update_dpp is the canonical (rocPRIM-exercised) DPP builtin; all controls
// used are total permutations within a row, so `old` is dead — pass src.
template <int CTRL>
__device__ __forceinline__ float dpp_add_f(float x) {
  const int xi = __builtin_bit_cast(int, x);
  const int y = __builtin_amdgcn_update_dpp(xi, xi, CTRL, 0xF, 0xF, true);
  return x + __builtin_bit_cast(float, y);
}
template <int CTRL>
__device__ __forceinline__ float dpp_max_f(float x) {
  const int xi = __builtin_bit_cast(int, x);
  const int y = __builtin_amdgcn_update_dpp(xi, xi, CTRL, 0xF, 0xF, true);
  return fmaxf(x, __builtin_bit_cast(float, y));
}

__device__ __forceinline__ float dot2h(unsigned kbits, unsigned qbits, float acc) {
#if __has_builtin(__builtin_amdgcn_fdot2)
  return __builtin_amdgcn_fdot2(__builtin_bit_cast(half2_t, kbits),
                                __builtin_bit_cast(half2_t, qbits), acc, false);
#else
  half2_t kk = __builtin_bit_cast(half2_t, kbits);
  half2_t qq = __builtin_bit_cast(half2_t, qbits);
  return acc + (float)kk.x * (float)qq.x + (float)kk.y * (float)qq.y;
#endif
}

#define GLOAD_LDS16(gp, lp)                                                  \
  __builtin_amdgcn_global_load_lds(                                          \
      (const __attribute__((address_space(1))) void*)(gp),                   \
      (__attribute__((address_space(3))) void*)(lp), 16, 0, 0)

// ---- launch 1: key_scores (blocks [0,512)) + f32->bf16 conversion (rest) ----
#define NSCORE (T_DIM / 4)  // 512
#define NCONV ((T_DIM * C_DIM + 4 * C_DIM * C_DIM) / 4 / 256)  // 6144
__global__ __launch_bounds__(256) void convert_scores_kernel(
    const float* __restrict__ x, const float* __restrict__ Wq,
    const float* __restrict__ Wk, const float* __restrict__ Wv,
    const float* __restrict__ Wo, const float* __restrict__ Wks,
    const float* __restrict__ bks,
    unsigned short* __restrict__ xb, unsigned short* __restrict__ Wqb,
    unsigned short* __restrict__ Wkb, unsigned short* __restrict__ Wvb,
    unsigned short* __restrict__ Wob, float* __restrict__ scores) {
  if (blockIdx.x < NSCORE) {
    const int t = blockIdx.x * 4 + (threadIdx.x >> 6);
    const int lane = threadIdx.x & 63;
    const float* xrow = x + (size_t)t * C_DIM;
    float acc = 0.f;
    #pragma unroll 4
    for (int i = lane; i < C_DIM; i += 64)
      acc += xrow[i] * Wks[i];
    #pragma unroll
    for (int o = 32; o; o >>= 1) acc += __shfl_xor(acc, o);
    if (lane == 0) scores[t] = acc + bks[0];
    return;
  }
  const int i = (blockIdx.x - NSCORE) * 256 + threadIdx.x;
  const int NX4 = T_DIM * C_DIM / 4;
  const int NW4 = C_DIM * C_DIM / 4;
  const float* src;
  unsigned short* dst;
  int j = i;
  if (j < NX4) { src = x; dst = xb; }
  else {
    j -= NX4;
    int w = j / NW4;
    j -= w * NW4;
    src = (w == 0) ? Wq : (w == 1) ? Wk : (w == 2) ? Wv : Wo;
    dst = (w == 0) ? Wqb : (w == 1) ? Wkb : (w == 2) ? Wvb : Wob;
  }
  float4 f = reinterpret_cast<const float4*>(src)[j];
  ushort4 o;
  o.x = f2bfu(f.x); o.y = f2bfu(f.y); o.z = f2bfu(f.z); o.w = f2bfu(f.w);
  reinterpret_cast<ushort4*>(dst)[j] = o;
}

// ---- GEMM body: 128x64 tile, BK=128; LDS passed in (shared arena) ----
__device__ __forceinline__ void gemm_body_128x64(
    const unsigned short* __restrict__ A, const unsigned short* __restrict__ W,
    f32x4 acc[4][2], int bm, int bn, int tid,
    unsigned short* As, unsigned short* Ws) {
  const int w = tid >> 6, lane = tid & 63;
  const int quad = lane >> 4, r = lane & 15;
  const int wm = (w >> 1) * 64, wn = (w & 1) * 32;
  const int sub = lane >> 4;
  const int c = lane & 15;
  const unsigned short* Arow[8];
  const unsigned short* Wrow[4];
  #pragma unroll
  for (int i = 0; i < 8; ++i) {
    const int row = w * 32 + i * 4 + sub;
    Arow[i] = A + (size_t)(bm * GBM + row) * C_DIM + ((c ^ (row & 7)) * 8);
  }
  #pragma unroll
  for (int i = 0; i < 4; ++i) {
    const int row = w * 16 + i * 4 + sub;
    Wrow[i] = W + (size_t)(bn * GBN + row) * C_DIM + ((c ^ (row & 7)) * 8);
  }
  for (int kb = 0; kb < C_DIM; kb += GBK) {
    #pragma unroll
    for (int i = 0; i < 8; ++i)
      GLOAD_LDS16(Arow[i] + kb, &As[(w * 32 + i * 4) * GBK]);
    #pragma unroll
    for (int i = 0; i < 4; ++i)
      GLOAD_LDS16(Wrow[i] + kb, &Ws[(w * 16 + i * 4) * GBK]);
    __syncthreads();
    #pragma unroll
    for (int ks = 0; ks < 4; ++ks) {
      const int pc = ((ks * 4 + quad) ^ (r & 7)) * 8;
      short8 af[4], bfr[2];
      #pragma unroll
      for (int mi = 0; mi < 4; ++mi)
        af[mi] = *reinterpret_cast<const short8*>(&As[(wm + mi * 16 + r) * GBK + pc]);
      #pragma unroll
      for (int ni = 0; ni < 2; ++ni)
        bfr[ni] = *reinterpret_cast<const short8*>(&Ws[(wn + ni * 16 + r) * GBK + pc]);
      #pragma unroll
      for (int mi = 0; mi < 4; ++mi)
        #pragma unroll
        for (int ni = 0; ni < 2; ++ni)
          acc[mi][ni] = __builtin_amdgcn_mfma_f32_16x16x32_bf16(af[mi], bfr[ni], acc[mi][ni], 0, 0, 0);
    }
    __syncthreads();
  }
}

// ---- launch 2: rank_sort (blocks [0,512)) + fused QKV GEMM (rest). ----
#define NRANK (T_DIM / 4)  // 512
__global__ __launch_bounds__(256) void gemm_qkv_rank_kernel(
    const unsigned short* __restrict__ A,
    const unsigned short* __restrict__ Wq, const unsigned short* __restrict__ Wk,
    const unsigned short* __restrict__ Wv,
    const float* __restrict__ bq, const float* __restrict__ bk,
    const float* __restrict__ bv,
    unsigned short* __restrict__ qo, unsigned short* __restrict__ ko,
    unsigned short* __restrict__ vo,
    const float* __restrict__ scores, int* __restrict__ sorted_idx) {
  __shared__ unsigned short lds[(GBM + GBN) * GBK];  // 48 KB arena
  const int tid = threadIdx.x;
  if (blockIdx.x < NRANK) {
    // rank-by-counting sort: one wave per element, lane-parallel scan
    float* ss = reinterpret_cast<float*>(lds);  // first 8 KB of arena
    for (int j = tid; j < T_DIM; j += 256) ss[j] = scores[j];
    __syncthreads();
    const int w = tid >> 6, lane = tid & 63;
    const int i = blockIdx.x * 4 + w;
    const float si = ss[i];
    int rank = 0;
    #pragma unroll
    for (int step = 0; step < T_DIM / 64; ++step) {
      const int j = step * 64 + lane;
      const float sj = ss[j];
      rank += (int)((sj > si) || (sj == si && j < i));
    }
    #pragma unroll
    for (int o = 32; o; o >>= 1) rank += __shfl_xor(rank, o);
    if (lane == 0) sorted_idx[rank] = i;
    return;
  }
  const int bid = blockIdx.x - NRANK;
  const int per = (T_DIM / GBM) * (C_DIM / GBN);  // 256
  const int which = bid / per;
  const int rem = bid % per;
  const int bm = rem / (C_DIM / GBN);
  const int bn = rem % (C_DIM / GBN);
  const unsigned short* W = (which == 0) ? Wq : (which == 1) ? Wk : Wv;
  const float* bias = (which == 0) ? bq : (which == 1) ? bk : bv;
  unsigned short* out = (which == 0) ? qo : (which == 1) ? ko : vo;
  f32x4 acc[4][2] = {};
  gemm_body_128x64(A, W, acc, bm, bn, tid, lds, lds + GBM * GBK);
  const int w = tid >> 6, lane = tid & 63;
  const int quad = lane >> 4, r = lane & 15;
  const int wm = (w >> 1) * 64, wn = (w & 1) * 32;
  #pragma unroll
  for (int mi = 0; mi < 4; ++mi) {
    #pragma unroll
    for (int ni = 0; ni < 2; ++ni) {
      const int col = bn * GBN + wn + ni * 16 + r;
      const float bf = bias[col];
      #pragma unroll
      for (int i = 0; i < 4; ++i) {
        const int row = bm * GBM + wm + mi * 16 + quad * 4 + i;
        const float val = acc[mi][ni][i] + bf;
        // q,k -> f16 (fdot2 path in attn); v -> bf16
        out[(size_t)row * C_DIM + col] = (which == 2) ? f2bfu(val) : f2h(val);
      }
    }
  }
}

// ---- o-proj GEMM body: 64x64 tile, BK=128 ----
__device__ __forceinline__ void gemm_body_64x64(
    const unsigned short* __restrict__ A, const unsigned short* __restrict__ W,
    f32x4 acc[2][2], int bm, int bn, int tid) {
  __shared__ unsigned short As[OBM * GBK];  // 16 KB
  __shared__ unsigned short Ws[OBN * GBK];  // 16 KB
  const int w = tid >> 6, lane = tid & 63;
  const int quad = lane >> 4, r = lane & 15;
  const int wm = (w >> 1) * 32, wn = (w & 1) * 32;
  const int sub = lane >> 4;
  const int c = lane & 15;
  const unsigned short* Arow[4];
  const unsigned short* Wrow[4];
  #pragma unroll
  for (int i = 0; i < 4; ++i) {
    const int row = w * 16 + i * 4 + sub;
    Arow[i] = A + (size_t)(bm * OBM + row) * C_DIM + ((c ^ (row & 7)) * 8);
    Wrow[i] = W + (size_t)(bn * OBN + row) * C_DIM + ((c ^ (row & 7)) * 8);
  }
  for (int kb = 0; kb < C_DIM; kb += GBK) {
    #pragma unroll
    for (int i = 0; i < 4; ++i)
      GLOAD_LDS16(Arow[i] + kb, &As[(w * 16 + i * 4) * GBK]);
    #pragma unroll
    for (int i = 0; i < 4; ++i)
      GLOAD_LDS16(Wrow[i] + kb, &Ws[(w * 16 + i * 4) * GBK]);
    __syncthreads();
    #pragma unroll
    for (int ks = 0; ks < 4; ++ks) {
      const int pc = ((ks * 4 + quad) ^ (r & 7)) * 8;
      short8 af[2], bfr[2];
      #pragma unroll
      for (int mi = 0; mi < 2; ++mi)
        af[mi] = *reinterpret_cast<const short8*>(&As[(wm + mi * 16 + r) * GBK + pc]);
      #pragma unroll
      for (int ni = 0; ni < 2; ++ni)
        bfr[ni] = *reinterpret_cast<const short8*>(&Ws[(wn + ni * 16 + r) * GBK + pc]);
      #pragma unroll
      for (int mi = 0; mi < 2; ++mi)
        #pragma unroll
        for (int ni = 0; ni < 2; ++ni)
          acc[mi][ni] = __builtin_amdgcn_mfma_f32_16x16x32_bf16(af[mi], bfr[ni], acc[mi][ni], 0, 0, 0);
    }
    __syncthreads();
  }
}

// ---- launch 5: output projection GEMM, fp32 out, 64x64 tile ----
__global__ __launch_bounds__(256) void gemm_o_f32_kernel(
    const unsigned short* __restrict__ A, const unsigned short* __restrict__ W,
    const float* __restrict__ bias, float* __restrict__ out) {
  const int tid = threadIdx.x;
  const int bm = blockIdx.x / (C_DIM / OBN);
  const int bn = blockIdx.x % (C_DIM / OBN);
  f32x4 acc[2][2] = {};
  gemm_body_64x64(A, W, acc, bm, bn, tid);
  const int w = tid >> 6, lane = tid & 63;
  const int quad = lane >> 4, r = lane & 15;
  const int wm = (w >> 1) * 32, wn = (w & 1) * 32;
  #pragma unroll
  for (int mi = 0; mi < 2; ++mi) {
    #pragma unroll
    for (int ni = 0; ni < 2; ++ni) {
      const int col = bn * OBN + wn + ni * 16 + r;
      const float bf = bias[col];
      #pragma unroll
      for (int i = 0; i < 4; ++i) {
        const int row = bm * OBM + wm + mi * 16 + quad * 4 + i;
        out[(size_t)row * C_DIM + col] = acc[mi][ni][i] + bf;
      }
    }
  }
}

// ---- launch 3: per-t top-64 selection (one wave per t, u16 row indices).
// Hoisted: computed once per t (2048 waves) instead of once per (t, head)
// inside attn (16x redundancy). ----
__global__ __launch_bounds__(256) void select_kernel(
    const int* __restrict__ sorted_idx, unsigned short* __restrict__ sel) {
  const int tid = threadIdx.x;
  const int w = tid >> 6, lane = tid & 63;
  const int t = blockIdx.x * 4 + w;
  unsigned short* dst = sel + (size_t)t * KSP;
  if (t <= 63) {
    // reference semantics: rows 0..t-1 once, row t duplicated (clamped -inf picks)
    dst[lane] = (unsigned short)((lane < t) ? lane : t);
    return;
  }
  const unsigned long long lt_mask = (1ull << lane) - 1ull;
  int count = 0;
  for (int c = 0; c < T_DIM / 64 && count < KSP; ++c) {
    int s = sorted_idx[c * 64 + lane];
    s = (s < 0) ? 0 : (s > T_DIM - 1 ? T_DIM - 1 : s);
    const bool ok = (s <= t);
    const unsigned long long mm = __ballot(ok);
    const int pos = count + __popcll(mm & lt_mask);
    if (ok && pos < KSP) dst[pos] = (unsigned short)s;
    count += __popcll(mm);
  }
}

// ---- launch 4: union-tiled sparse attention v4.
// Block = (16 t's, one head); selections precomputed (no scan). Union slots
// positional: slot j<64 = sel(t0)[j], slots 64..78 = rows t0+1..t0+15.
// Intra-16 reductions on the VALU pipe via DPP (quad_perm / half_mirror /
// row_ror:8) — only xor16/xor32 remain as DS shuffles. ----
__global__ __launch_bounds__(256) void attn_kernel(
    const unsigned short* __restrict__ q, const unsigned short* __restrict__ k,
    const unsigned short* __restrict__ v, const unsigned short* __restrict__ sel,
    unsigned short* __restrict__ attn_out) {
  __shared__ unsigned short Kl[USLOT * KSTR];  // 10428 B
  __shared__ unsigned short Vl[USLOT * KSTR];  // 10428 B
  __shared__ short map_s[T_DIM];               // 4 KB; only union entries written
  __shared__ short urows[USLOT];
  const int tb = blockIdx.x >> 4;
  const int h = blockIdx.x & (NH - 1);
  const int t0 = tb * ATB;
  const int tid = threadIdx.x;
  const int w = tid >> 6, lane = tid & 63;
  const int c8 = lane & 7;
  const int ksub = lane >> 3;
  // hoist Q loads (independent of all LDS phases)
  uint4 qr[ATB / 4];
  #pragma unroll
  for (int li = 0; li < ATB / 4; ++li) {
    const int t = t0 + w * (ATB / 4) + li;
    qr[li] = *reinterpret_cast<const uint4*>(q + (size_t)t * C_DIM + h * HS + 8 * c8);
  }
  // phase A: positional union build (no scan). Dup rows (t0<64) race-write
  // map_s benignly: all winning slots hold identical row data.
  if (tid < KSP) {
    const int r0 = sel[(size_t)t0 * KSP + tid];
    map_s[r0] = (short)tid;
    urows[tid] = (short)r0;
  } else if (tid < USLOT) {
    const int row = t0 + 1 + (tid - KSP);
    map_s[row] = (short)tid;
    urows[tid] = (short)row;
  }
  __syncthreads();
  // phase B: gather union K/V head slices into LDS (8 lanes per row)
  {
    const int e8 = tid & 7;
    for (int s = tid >> 3; s < USLOT; s += 32) {
      const int row = urows[s];
      const size_t gb = (size_t)row * C_DIM + h * HS + e8 * 8;
      *reinterpret_cast<uint4*>(&Kl[s * KSTR + e8 * 8]) =
          *reinterpret_cast<const uint4*>(k + gb);
      *reinterpret_cast<uint4*>(&Vl[s * KSTR + e8 * 8]) =
          *reinterpret_cast<const uint4*>(v + gb);
    }
  }
  __syncthreads();
  // phase C: compute 4 t's per wave, all K/V from LDS, DPP reductions
  #pragma unroll 2
  for (int li = 0; li < ATB / 4; ++li) {
    const int tt = w * (ATB / 4) + li;
    const int t = t0 + tt;
    const uint4 qraw = qr[li];
    const unsigned short* __restrict__ selt = sel + (size_t)t * KSP;
    int slot[8];
    #pragma unroll
    for (int jj = 0; jj < 8; ++jj)
      slot[jj] = map_s[selt[8 * jj + ksub]];
    // phase 1: logits via f16 dot2 from LDS K; c8-group reduce on VALU (DPP)
    float l[8];
    #pragma unroll
    for (int jj = 0; jj < 8; ++jj) {
      const uint4 raw =
          *reinterpret_cast<const uint4*>(&Kl[slot[jj] * KSTR + 8 * c8]);
      float pl = dot2h(raw.x, qraw.x, 0.f);
      pl = dot2h(raw.y, qraw.y, pl);
      pl = dot2h(raw.z, qraw.z, pl);
      pl = dot2h(raw.w, qraw.w, pl);
      pl *= 0.125f;
      pl = dpp_add_f<DPP_XOR1>(pl);
      pl = dpp_add_f<DPP_XOR2>(pl);
      pl = dpp_add_f<DPP_HMIRR>(pl);
      l[jj] = pl;
    }
    float m = l[0];
    #pragma unroll
    for (int jj = 1; jj < 8; ++jj) m = fmaxf(m, l[jj]);
    m = dpp_max_f<DPP_ROR8>(m);
    m = fmaxf(m, __shfl_xor(m, 16));
    m = fmaxf(m, __shfl_xor(m, 32));
    float sum = 0.f;
    #pragma unroll
    for (int jj = 0; jj < 8; ++jj) {
      l[jj] = __expf(l[jj] - m);
      sum += l[jj];
    }
    sum = dpp_add_f<DPP_ROR8>(sum);
    sum += __shfl_xor(sum, 16);
    sum += __shfl_xor(sum, 32);
    const float rs = 1.0f / sum;
    // phase 2: weighted V (bf16) sum from LDS V
    float a[8] = {0.f, 0.f, 0.f, 0.f, 0.f, 0.f, 0.f, 0.f};
    #pragma unroll
    for (int jj = 0; jj < 8; ++jj) {
      const uint4 raw =
          *reinterpret_cast<const uint4*>(&Vl[slot[jj] * KSTR + 8 * c8]);
      const float p = l[jj] * rs;
      a[0] += p * bflo(raw.x); a[1] += p * bfhi(raw.x);
      a[2] += p * bflo(raw.y); a[3] += p * bfhi(raw.y);
      a[4] += p * bflo(raw.z); a[5] += p * bfhi(raw.z);
      a[6] += p * bflo(raw.w); a[7] += p * bfhi(raw.w);
    }
    #pragma unroll
    for (int z = 0; z < 8; ++z) a[z] = dpp_add_f<DPP_ROR8>(a[z]);
    #pragma unroll
    for (int z = 0; z < 8; ++z) a[z] += __shfl_xor(a[z], 16);
    #pragma unroll
    for (int z = 0; z < 8; ++z) a[z] += __shfl_xor(a[z], 32);
    if (ksub == 0) {
      ushort4 o0, o1;
      o0.x = f2bfu(a[0]); o0.y = f2bfu(a[1]); o0.z = f2bfu(a[2]); o0.w = f2bfu(a[3]);
      o1.x = f2bfu(a[4]); o1.y = f2bfu(a[5]); o1.z = f2bfu(a[6]); o1.w = f2bfu(a[7]);
      ushort4* dst =
          reinterpret_cast<ushort4*>(attn_out + (size_t)t * C_DIM + h * HS + 8 * c8);
      dst[0] = o0;
      dst[1] = o1;
    }
  }
}

extern "C" void kernel_launch(void* const* d_in, const int* in_sizes, int n_in,
                              void* d_out, int out_size, void* d_ws, size_t ws_size,
                              hipStream_t stream) {
  const float* x   = (const float*)d_in[0];
  const float* Wq  = (const float*)d_in[1];
  const float* bq  = (const float*)d_in[2];
  const float* Wk  = (const float*)d_in[3];
  const float* bk  = (const float*)d_in[4];
  const float* Wv  = (const float*)d_in[5];
  const float* bv  = (const float*)d_in[6];
  const float* Wo  = (const float*)d_in[7];
  const float* bo  = (const float*)d_in[8];
  const float* Wks = (const float*)d_in[9];
  const float* bks = (const float*)d_in[10];
  float* out = (float*)d_out;

  char* ws = (char*)d_ws;
  size_t off = 0;
  float* scores = (float*)(ws + off); off += 8192;
  int*   sorted = (int*)(ws + off);   off += 8192;
  unsigned short* selb = (unsigned short*)(ws + off); off += (size_t)T_DIM * KSP * 2;
  unsigned short* xb  = (unsigned short*)(ws + off); off += (size_t)T_DIM * C_DIM * 2;
  unsigned short* Wqb = (unsigned short*)(ws + off); off += (size_t)C_DIM * C_DIM * 2;
  unsigned short* Wkb = (unsigned short*)(ws + off); off += (size_t)C_DIM * C_DIM * 2;
  unsigned short* Wvb = (unsigned short*)(ws + off); off += (size_t)C_DIM * C_DIM * 2;
  unsigned short* Wob = (unsigned short*)(ws + off); off += (size_t)C_DIM * C_DIM * 2;
  unsigned short* qb  = (unsigned short*)(ws + off); off += (size_t)T_DIM * C_DIM * 2;
  unsigned short* kb  = (unsigned short*)(ws + off); off += (size_t)T_DIM * C_DIM * 2;
  unsigned short* vb  = (unsigned short*)(ws + off); off += (size_t)T_DIM * C_DIM * 2;
  unsigned short* ab  = xb;  // alias: xb dead after gemm_qkv

  // launch 1: conversion + scores
  convert_scores_kernel<<<NSCORE + NCONV, 256, 0, stream>>>(
      x, Wq, Wk, Wv, Wo, Wks, bks, xb, Wqb, Wkb, Wvb, Wob, scores);

  // launch 2: rank-sort (512 blocks) + fused QKV GEMM (768 blocks)
  gemm_qkv_rank_kernel<<<NRANK + 3 * (T_DIM / GBM) * (C_DIM / GBN), 256, 0,
                         stream>>>(
      xb, Wqb, Wkb, Wvb, bq, bk, bv, qb, kb, vb, scores, sorted);

  // launch 3: per-t top-64 selection (one wave per t)
  select_kernel<<<T_DIM / 4, 256, 0, stream>>>(sorted, selb);

  // launch 4: union-tiled attention (128 t-tiles x 16 heads = 2048 blocks)
  attn_kernel<<<(T_DIM / ATB) * NH, 256, 0, stream>>>(qb, kb, vb, selb, ab);

  // launch 5: output projection
  gemm_o_f32_kernel<<<(T_DIM / OBM) * (C_DIM / OBN), 256, 0, stream>>>(
      ab, Wob, bo, out);
}

// Round 6
// 149.858 us; speedup vs baseline: 1.1400x; 1.0729x over previous
//
#include <hip/hip_runtime.h>
#include <hip/hip_bf16.h>
#include <cstdint>
#include <cstddef>

#define T_DIM 2048
#define C_DIM 1024
#define NH 16
#define HS 64
#define KSP 64

// QKV GEMM: 128x64 tile, BK=128, XOR-swizzled LDS, global_load_lds staging
#define GBM 128
#define GBN 64
#define GBK 128
// o-proj GEMM: 64x64 tile (512 blocks = 2/CU)
#define OBM 64
#define OBN 64

// attention tiling: ATB=16 consecutive t's per block, 2 heads (1 per wave).
// union(tile) = sel(t0) UNION {t0+1..t0+15} (prefix property) -> positional
// slots 0..78; slot 79 = pad (row t0 data, cnt=0 -> masked).
#define ATB 16
#define KLS 72    // Kl row stride (shorts): 144B rows spread banks w/ swizzle
#define VTS 108   // Vt row stride (shorts): 216B -> bank stride 22, ~2-way
#define PLS 104   // Pl row stride (shorts): 208B, 16B-aligned b128 reads
#define CNS 104   // cnt row stride (dwords)

typedef short short8 __attribute__((ext_vector_type(8)));
typedef float f32x4 __attribute__((ext_vector_type(4)));
typedef _Float16 half8 __attribute__((ext_vector_type(8)));

__device__ __forceinline__ unsigned short f2bfu(float f) {
  unsigned u = __builtin_bit_cast(unsigned, f);
  unsigned r = (u + 0x7fffu + ((u >> 16) & 1u)) >> 16;
  return (unsigned short)r;
}
__device__ __forceinline__ unsigned short f2h(float f) {
  _Float16 h = (_Float16)f;
  return __builtin_bit_cast(unsigned short, h);
}

#define GLOAD_LDS16(gp, lp)                                                  \
  __builtin_amdgcn_global_load_lds(                                          \
      (const __attribute__((address_space(1))) void*)(gp),                   \
      (__attribute__((address_space(3))) void*)(lp), 16, 0, 0)

// ---- launch 1: key_scores (blocks [0,512)) + f32->bf16 conversion (rest) ----
#define NSCORE (T_DIM / 4)  // 512
#define NCONV ((T_DIM * C_DIM + 4 * C_DIM * C_DIM) / 4 / 256)  // 6144
__global__ __launch_bounds__(256) void convert_scores_kernel(
    const float* __restrict__ x, const float* __restrict__ Wq,
    const float* __restrict__ Wk, const float* __restrict__ Wv,
    const float* __restrict__ Wo, const float* __restrict__ Wks,
    const float* __restrict__ bks,
    unsigned short* __restrict__ xb, unsigned short* __restrict__ Wqb,
    unsigned short* __restrict__ Wkb, unsigned short* __restrict__ Wvb,
    unsigned short* __restrict__ Wob, float* __restrict__ scores) {
  if (blockIdx.x < NSCORE) {
    const int t = blockIdx.x * 4 + (threadIdx.x >> 6);
    const int lane = threadIdx.x & 63;
    const float* xrow = x + (size_t)t * C_DIM;
    float acc = 0.f;
    #pragma unroll 4
    for (int i = lane; i < C_DIM; i += 64)
      acc += xrow[i] * Wks[i];
    #pragma unroll
    for (int o = 32; o; o >>= 1) acc += __shfl_xor(acc, o);
    if (lane == 0) scores[t] = acc + bks[0];
    return;
  }
  const int i = (blockIdx.x - NSCORE) * 256 + threadIdx.x;
  const int NX4 = T_DIM * C_DIM / 4;
  const int NW4 = C_DIM * C_DIM / 4;
  const float* src;
  unsigned short* dst;
  int j = i;
  if (j < NX4) { src = x; dst = xb; }
  else {
    j -= NX4;
    int w = j / NW4;
    j -= w * NW4;
    src = (w == 0) ? Wq : (w == 1) ? Wk : (w == 2) ? Wv : Wo;
    dst = (w == 0) ? Wqb : (w == 1) ? Wkb : (w == 2) ? Wvb : Wob;
  }
  float4 f = reinterpret_cast<const float4*>(src)[j];
  ushort4 o;
  o.x = f2bfu(f.x); o.y = f2bfu(f.y); o.z = f2bfu(f.z); o.w = f2bfu(f.w);
  reinterpret_cast<ushort4*>(dst)[j] = o;
}

// ---- GEMM body: 128x64 tile, BK=128; LDS passed in (shared arena) ----
__device__ __forceinline__ void gemm_body_128x64(
    const unsigned short* __restrict__ A, const unsigned short* __restrict__ W,
    f32x4 acc[4][2], int bm, int bn, int tid,
    unsigned short* As, unsigned short* Ws) {
  const int w = tid >> 6, lane = tid & 63;
  const int quad = lane >> 4, r = lane & 15;
  const int wm = (w >> 1) * 64, wn = (w & 1) * 32;
  const int sub = lane >> 4;
  const int c = lane & 15;
  const unsigned short* Arow[8];
  const unsigned short* Wrow[4];
  #pragma unroll
  for (int i = 0; i < 8; ++i) {
    const int row = w * 32 + i * 4 + sub;
    Arow[i] = A + (size_t)(bm * GBM + row) * C_DIM + ((c ^ (row & 7)) * 8);
  }
  #pragma unroll
  for (int i = 0; i < 4; ++i) {
    const int row = w * 16 + i * 4 + sub;
    Wrow[i] = W + (size_t)(bn * GBN + row) * C_DIM + ((c ^ (row & 7)) * 8);
  }
  for (int kb = 0; kb < C_DIM; kb += GBK) {
    #pragma unroll
    for (int i = 0; i < 8; ++i)
      GLOAD_LDS16(Arow[i] + kb, &As[(w * 32 + i * 4) * GBK]);
    #pragma unroll
    for (int i = 0; i < 4; ++i)
      GLOAD_LDS16(Wrow[i] + kb, &Ws[(w * 16 + i * 4) * GBK]);
    __syncthreads();
    #pragma unroll
    for (int ks = 0; ks < 4; ++ks) {
      const int pc = ((ks * 4 + quad) ^ (r & 7)) * 8;
      short8 af[4], bfr[2];
      #pragma unroll
      for (int mi = 0; mi < 4; ++mi)
        af[mi] = *reinterpret_cast<const short8*>(&As[(wm + mi * 16 + r) * GBK + pc]);
      #pragma unroll
      for (int ni = 0; ni < 2; ++ni)
        bfr[ni] = *reinterpret_cast<const short8*>(&Ws[(wn + ni * 16 + r) * GBK + pc]);
      #pragma unroll
      for (int mi = 0; mi < 4; ++mi)
        #pragma unroll
        for (int ni = 0; ni < 2; ++ni)
          acc[mi][ni] = __builtin_amdgcn_mfma_f32_16x16x32_bf16(af[mi], bfr[ni], acc[mi][ni], 0, 0, 0);
    }
    __syncthreads();
  }
}

// ---- launch 2: rank_sort (blocks [0,512)) + fused QKV GEMM (rest). ----
#define NRANK (T_DIM / 4)  // 512
__global__ __launch_bounds__(256) void gemm_qkv_rank_kernel(
    const unsigned short* __restrict__ A,
    const unsigned short* __restrict__ Wq, const unsigned short* __restrict__ Wk,
    const unsigned short* __restrict__ Wv,
    const float* __restrict__ bq, const float* __restrict__ bk,
    const float* __restrict__ bv,
    unsigned short* __restrict__ qo, unsigned short* __restrict__ ko,
    unsigned short* __restrict__ vo,
    const float* __restrict__ scores, int* __restrict__ sorted_idx) {
  __shared__ unsigned short lds[(GBM + GBN) * GBK];  // 48 KB arena
  const int tid = threadIdx.x;
  if (blockIdx.x < NRANK) {
    // rank-by-counting sort: one wave per element, lane-parallel scan
    float* ss = reinterpret_cast<float*>(lds);  // first 8 KB of arena
    for (int j = tid; j < T_DIM; j += 256) ss[j] = scores[j];
    __syncthreads();
    const int w = tid >> 6, lane = tid & 63;
    const int i = blockIdx.x * 4 + w;
    const float si = ss[i];
    int rank = 0;
    #pragma unroll
    for (int step = 0; step < T_DIM / 64; ++step) {
      const int j = step * 64 + lane;
      const float sj = ss[j];
      rank += (int)((sj > si) || (sj == si && j < i));
    }
    #pragma unroll
    for (int o = 32; o; o >>= 1) rank += __shfl_xor(rank, o);
    if (lane == 0) sorted_idx[rank] = i;
    return;
  }
  const int bid = blockIdx.x - NRANK;
  const int per = (T_DIM / GBM) * (C_DIM / GBN);  // 256
  const int which = bid / per;
  const int rem = bid % per;
  const int bm = rem / (C_DIM / GBN);
  const int bn = rem % (C_DIM / GBN);
  const unsigned short* W = (which == 0) ? Wq : (which == 1) ? Wk : Wv;
  const float* bias = (which == 0) ? bq : (which == 1) ? bk : bv;
  unsigned short* out = (which == 0) ? qo : (which == 1) ? ko : vo;
  f32x4 acc[4][2] = {};
  gemm_body_128x64(A, W, acc, bm, bn, tid, lds, lds + GBM * GBK);
  const int w = tid >> 6, lane = tid & 63;
  const int quad = lane >> 4, r = lane & 15;
  const int wm = (w >> 1) * 64, wn = (w & 1) * 32;
  #pragma unroll
  for (int mi = 0; mi < 4; ++mi) {
    #pragma unroll
    for (int ni = 0; ni < 2; ++ni) {
      const int col = bn * GBN + wn + ni * 16 + r;
      const float bf = bias[col];
      #pragma unroll
      for (int i = 0; i < 4; ++i) {
        const int row = bm * GBM + wm + mi * 16 + quad * 4 + i;
        const float val = acc[mi][ni][i] + bf;
        // q,k,v all f16 now (MFMA f16 path in attn; f16 V >= bf16 precision)
        out[(size_t)row * C_DIM + col] = f2h(val);
      }
    }
  }
}

// ---- o-proj GEMM body: 64x64 tile, BK=128 ----
__device__ __forceinline__ void gemm_body_64x64(
    const unsigned short* __restrict__ A, const unsigned short* __restrict__ W,
    f32x4 acc[2][2], int bm, int bn, int tid) {
  __shared__ unsigned short As[OBM * GBK];  // 16 KB
  __shared__ unsigned short Ws[OBN * GBK];  // 16 KB
  const int w = tid >> 6, lane = tid & 63;
  const int quad = lane >> 4, r = lane & 15;
  const int wm = (w >> 1) * 32, wn = (w & 1) * 32;
  const int sub = lane >> 4;
  const int c = lane & 15;
  const unsigned short* Arow[4];
  const unsigned short* Wrow[4];
  #pragma unroll
  for (int i = 0; i < 4; ++i) {
    const int row = w * 16 + i * 4 + sub;
    Arow[i] = A + (size_t)(bm * OBM + row) * C_DIM + ((c ^ (row & 7)) * 8);
    Wrow[i] = W + (size_t)(bn * OBN + row) * C_DIM + ((c ^ (row & 7)) * 8);
  }
  for (int kb = 0; kb < C_DIM; kb += GBK) {
    #pragma unroll
    for (int i = 0; i < 4; ++i)
      GLOAD_LDS16(Arow[i] + kb, &As[(w * 16 + i * 4) * GBK]);
    #pragma unroll
    for (int i = 0; i < 4; ++i)
      GLOAD_LDS16(Wrow[i] + kb, &Ws[(w * 16 + i * 4) * GBK]);
    __syncthreads();
    #pragma unroll
    for (int ks = 0; ks < 4; ++ks) {
      const int pc = ((ks * 4 + quad) ^ (r & 7)) * 8;
      short8 af[2], bfr[2];
      #pragma unroll
      for (int mi = 0; mi < 2; ++mi)
        af[mi] = *reinterpret_cast<const short8*>(&As[(wm + mi * 16 + r) * GBK + pc]);
      #pragma unroll
      for (int ni = 0; ni < 2; ++ni)
        bfr[ni] = *reinterpret_cast<const short8*>(&Ws[(wn + ni * 16 + r) * GBK + pc]);
      #pragma unroll
      for (int mi = 0; mi < 2; ++mi)
        #pragma unroll
        for (int ni = 0; ni < 2; ++ni)
          acc[mi][ni] = __builtin_amdgcn_mfma_f32_16x16x32_bf16(af[mi], bfr[ni], acc[mi][ni], 0, 0, 0);
    }
    __syncthreads();
  }
}

// ---- launch 5: output projection GEMM, fp32 out, 64x64 tile ----
__global__ __launch_bounds__(256) void gemm_o_f32_kernel(
    const unsigned short* __restrict__ A, const unsigned short* __restrict__ W,
    const float* __restrict__ bias, float* __restrict__ out) {
  const int tid = threadIdx.x;
  const int bm = blockIdx.x / (C_DIM / OBN);
  const int bn = blockIdx.x % (C_DIM / OBN);
  f32x4 acc[2][2] = {};
  gemm_body_64x64(A, W, acc, bm, bn, tid);
  const int w = tid >> 6, lane = tid & 63;
  const int quad = lane >> 4, r = lane & 15;
  const int wm = (w >> 1) * 32, wn = (w & 1) * 32;
  #pragma unroll
  for (int mi = 0; mi < 2; ++mi) {
    #pragma unroll
    for (int ni = 0; ni < 2; ++ni) {
      const int col = bn * OBN + wn + ni * 16 + r;
      const float bf = bias[col];
      #pragma unroll
      for (int i = 0; i < 4; ++i) {
        const int row = bm * OBM + wm + mi * 16 + quad * 4 + i;
        out[(size_t)row * C_DIM + col] = acc[mi][ni][i] + bf;
      }
    }
  }
}

// ---- launch 3: per-t top-64 selection (one wave per t, u16 row indices) ----
__global__ __launch_bounds__(256) void select_kernel(
    const int* __restrict__ sorted_idx, unsigned short* __restrict__ sel) {
  const int tid = threadIdx.x;
  const int w = tid >> 6, lane = tid & 63;
  const int t = blockIdx.x * 4 + w;
  unsigned short* dst = sel + (size_t)t * KSP;
  if (t <= 63) {
    // reference semantics: rows 0..t-1 once, row t duplicated (clamped -inf picks)
    dst[lane] = (unsigned short)((lane < t) ? lane : t);
    return;
  }
  const unsigned long long lt_mask = (1ull << lane) - 1ull;
  int count = 0;
  for (int c = 0; c < T_DIM / 64 && count < KSP; ++c) {
    int s = sorted_idx[c * 64 + lane];
    s = (s < 0) ? 0 : (s > T_DIM - 1 ? T_DIM - 1 : s);
    const bool ok = (s <= t);
    const unsigned long long mm = __ballot(ok);
    const int pos = count + __popcll(mm & lt_mask);
    if (ok && pos < KSP) dst[pos] = (unsigned short)s;
    count += __popcll(mm);
  }
}

// ---- launch 4: MFMA sparse attention.
// Block = (16 t's, 2 heads), 128 threads; wave w = head hg*2+w. Union of the
// 16 selections staged once: K swizzled row-major (QK^T A-operand), V
// TRANSPOSED Vt[d][u] (PV A-operand). Mask/multiplicity via cnt[t][u] table
// (bias = ln(cnt), cnt=0 -> -inf): exact reference semantics incl. t<64 dups.
// S^T = K @ Q^T (10 mfma) -> lane-local row softmax (t = lane&15, 2 shfl)
// -> P f16 via Pl LDS roundtrip -> O^T = Vt @ P (12 mfma). Replaces ~300
// VALU/t with 22 MFMA per 16 t's. ----
__global__ __launch_bounds__(128) void attn_kernel(
    const unsigned short* __restrict__ q, const unsigned short* __restrict__ k,
    const unsigned short* __restrict__ v, const unsigned short* __restrict__ sel,
    unsigned short* __restrict__ attn_out) {
  __shared__ unsigned short Kl[2][80 * KLS];   // 2 x 11520 B
  __shared__ unsigned short Vt[2][64 * VTS];   // 2 x 13824 B
  __shared__ unsigned short Pl[2][16 * PLS];   // 2 x 3328 B
  __shared__ unsigned int   cnt[16 * CNS];     // 6656 B
  __shared__ short map_s[T_DIM];               // 4 KB
  __shared__ short urows[80];
  const int tb = blockIdx.x >> 3;
  const int hg = blockIdx.x & 7;
  const int t0 = tb * ATB;
  const int tid = threadIdx.x;
  const int w = tid >> 6, lane = tid & 63;
  const int qd = lane >> 4;      // quad
  const int r = lane & 15;
  const int h = hg * 2 + w;

  // hoist Q B-frags (global f16): lane (qd,r) holds Q[t0+r][kc*32+qd*8 ..+7]
  uint4 qf[2];
  #pragma unroll
  for (int kc = 0; kc < 2; ++kc)
    qf[kc] = *reinterpret_cast<const uint4*>(
        q + (size_t)(t0 + r) * C_DIM + h * HS + kc * 32 + qd * 8);

  // phase A: positional union slots + zero cnt
  if (tid < KSP) {
    const int r0 = sel[(size_t)t0 * KSP + tid];
    map_s[r0] = (short)tid;  // dup rows (t0<64) race benignly: identical data
    urows[tid] = (short)r0;
  } else if (tid < 79) {
    const int row = t0 + 1 + (tid - KSP);
    map_s[row] = (short)tid;
    urows[tid] = (short)row;
  } else if (tid == 79) {
    urows[79] = (short)t0;   // pad slot: real data, cnt stays 0 -> masked
  }
  for (int i = tid; i < 16 * CNS; i += 128) cnt[i] = 0u;
  __syncthreads();

  // phase B: per-wave K/V gather (row pairs) + shared cnt build + pad zeroing
  {
    const int e8 = lane & 7;
    const int pr = lane >> 3;  // row-pair id 0..7
    #pragma unroll
    for (int sb = 0; sb < 5; ++sb) {
      const int s0 = sb * 16 + pr * 2;
      const int row0 = urows[s0], row1 = urows[s0 + 1];
      const size_t g0 = (size_t)row0 * C_DIM + h * HS + e8 * 8;
      const size_t g1 = (size_t)row1 * C_DIM + h * HS + e8 * 8;
      const uint4 k0 = *reinterpret_cast<const uint4*>(k + g0);
      const uint4 k1 = *reinterpret_cast<const uint4*>(k + g1);
      const uint4 v0 = *reinterpret_cast<const uint4*>(v + g0);
      const uint4 v1 = *reinterpret_cast<const uint4*>(v + g1);
      *reinterpret_cast<uint4*>(&Kl[w][s0 * KLS + ((e8 ^ (s0 & 7)) * 8)]) = k0;
      *reinterpret_cast<uint4*>(&Kl[w][(s0 + 1) * KLS + ((e8 ^ ((s0 + 1) & 7)) * 8)]) = k1;
      const unsigned* v0w = reinterpret_cast<const unsigned*>(&v0);
      const unsigned* v1w = reinterpret_cast<const unsigned*>(&v1);
      // transpose-scatter: Vt[d][s0..s0+1] as one u32 (pair-packed)
      #pragma unroll
      for (int dd = 0; dd < 8; ++dd) {
        const unsigned lo = (v0w[dd >> 1] >> ((dd & 1) * 16)) & 0xffffu;
        const unsigned hi = (v1w[dd >> 1] >> ((dd & 1) * 16)) & 0xffffu;
        *reinterpret_cast<unsigned*>(&Vt[w][(e8 * 8 + dd) * VTS + s0]) =
            lo | (hi << 16);
      }
    }
    // zero Vt pad cols u=80..95 (k-chunk 2 covers u 64..95)
    #pragma unroll
    for (int z = 0; z < 4; ++z)
      *reinterpret_cast<unsigned long long*>(&Vt[w][lane * VTS + 80 + z * 4]) = 0ull;
    // cnt build: 16t x 64 entries; multiplicities >1 only when t0<64
    if (t0 < 64) {
      #pragma unroll
      for (int e = 0; e < 8; ++e) {
        const int idx = tid + e * 128;
        const int tl = idx >> 6;
        const int rr = sel[(size_t)(t0 + tl) * KSP + (idx & 63)];
        atomicAdd(&cnt[tl * CNS + map_s[rr]], 1u);
      }
    } else {
      #pragma unroll
      for (int e = 0; e < 8; ++e) {
        const int idx = tid + e * 128;
        const int tl = idx >> 6;
        const int rr = sel[(size_t)(t0 + tl) * KSP + (idx & 63)];
        cnt[tl * CNS + map_s[rr]] = 1u;  // distinct rows -> no race
      }
    }
  }
  __syncthreads();

  // phase C (per wave): S^T = K @ Q^T; lane holds S[u=ut*16+qd*4+i][t=r]
  f32x4 s5[5] = {};
  #pragma unroll
  for (int ut = 0; ut < 5; ++ut) {
    #pragma unroll
    for (int kc = 0; kc < 2; ++kc) {
      const uint4 kw = *reinterpret_cast<const uint4*>(
          &Kl[w][(ut * 16 + r) * KLS + (((kc * 4 + qd) ^ (r & 7)) * 8)]);
      s5[ut] = __builtin_amdgcn_mfma_f32_16x16x32_f16(
          __builtin_bit_cast(half8, kw), __builtin_bit_cast(half8, qf[kc]),
          s5[ut], 0, 0, 0);
    }
  }
  // bias (mask/multiplicity) + row-max
  float mx = -3.0e38f;
  #pragma unroll
  for (int ut = 0; ut < 5; ++ut) {
    const uint4 c4 = *reinterpret_cast<const uint4*>(&cnt[r * CNS + ut * 16 + qd * 4]);
    const unsigned cc[4] = {c4.x, c4.y, c4.z, c4.w};
    #pragma unroll
    for (int i = 0; i < 4; ++i) {
      float lg = s5[ut][i] * 0.125f;
      lg = (cc[i] == 0u) ? -3.0e38f
         : (cc[i] == 1u) ? lg : (lg + __logf((float)cc[i]));
      s5[ut][i] = lg;
      mx = fmaxf(mx, lg);
    }
  }
  mx = fmaxf(mx, __shfl_xor(mx, 16));
  mx = fmaxf(mx, __shfl_xor(mx, 32));
  float sum = 0.f;
  #pragma unroll
  for (int ut = 0; ut < 5; ++ut)
    #pragma unroll
    for (int i = 0; i < 4; ++i) {
      const float e = __expf(s5[ut][i] - mx);
      s5[ut][i] = e;
      sum += e;
    }
  sum += __shfl_xor(sum, 16);
  sum += __shfl_xor(sum, 32);
  const float rs = 1.0f / sum;
  // P -> f16 into Pl[t][u] (wave-local roundtrip; no barrier needed)
  #pragma unroll
  for (int ut = 0; ut < 5; ++ut) {
    const unsigned w0 = (unsigned)f2h(s5[ut][0] * rs) |
                        ((unsigned)f2h(s5[ut][1] * rs) << 16);
    const unsigned w1 = (unsigned)f2h(s5[ut][2] * rs) |
                        ((unsigned)f2h(s5[ut][3] * rs) << 16);
    unsigned* p32 = reinterpret_cast<unsigned*>(&Pl[w][r * PLS + ut * 16 + qd * 4]);
    p32[0] = w0;
    p32[1] = w1;
  }
  // zero Pl pad u=80..95 (4 shorts per quad)
  *reinterpret_cast<unsigned long long*>(&Pl[w][r * PLS + 80 + qd * 4]) = 0ull;
  // PV: O^T[d][t] = Vt @ P; A = Vt rows (d), B = Pl cols (t)
  f32x4 o4[4] = {};
  #pragma unroll
  for (int c = 0; c < 3; ++c) {
    const uint4 pw = *reinterpret_cast<const uint4*>(&Pl[w][r * PLS + c * 32 + qd * 8]);
    #pragma unroll
    for (int mt = 0; mt < 4; ++mt) {
      const uint2 lo = *reinterpret_cast<const uint2*>(
          &Vt[w][(mt * 16 + r) * VTS + c * 32 + qd * 8]);
      const uint2 hi = *reinterpret_cast<const uint2*>(
          &Vt[w][(mt * 16 + r) * VTS + c * 32 + qd * 8 + 4]);
      const uint4 vw = {lo.x, lo.y, hi.x, hi.y};
      o4[mt] = __builtin_amdgcn_mfma_f32_16x16x32_f16(
          __builtin_bit_cast(half8, vw), __builtin_bit_cast(half8, pw),
          o4[mt], 0, 0, 0);
    }
  }
  // store: lane holds O[t=r][d = mt*16 + qd*4 + i], bf16 out
  #pragma unroll
  for (int mt = 0; mt < 4; ++mt) {
    ushort4 ov;
    ov.x = f2bfu(o4[mt][0]); ov.y = f2bfu(o4[mt][1]);
    ov.z = f2bfu(o4[mt][2]); ov.w = f2bfu(o4[mt][3]);
    *reinterpret_cast<ushort4*>(
        attn_out + (size_t)(t0 + r) * C_DIM + h * HS + mt * 16 + qd * 4) = ov;
  }
}

extern "C" void kernel_launch(void* const* d_in, const int* in_sizes, int n_in,
                              void* d_out, int out_size, void* d_ws, size_t ws_size,
                              hipStream_t stream) {
  const float* x   = (const float*)d_in[0];
  const float* Wq  = (const float*)d_in[1];
  const float* bq  = (const float*)d_in[2];
  const float* Wk  = (const float*)d_in[3];
  const float* bk  = (const float*)d_in[4];
  const float* Wv  = (const float*)d_in[5];
  const float* bv  = (const float*)d_in[6];
  const float* Wo  = (const float*)d_in[7];
  const float* bo  = (const float*)d_in[8];
  const float* Wks = (const float*)d_in[9];
  const float* bks = (const float*)d_in[10];
  float* out = (float*)d_out;

  char* ws = (char*)d_ws;
  size_t off = 0;
  float* scores = (float*)(ws + off); off += 8192;
  int*   sorted = (int*)(ws + off);   off += 8192;
  unsigned short* selb = (unsigned short*)(ws + off); off += (size_t)T_DIM * KSP * 2;
  unsigned short* xb  = (unsigned short*)(ws + off); off += (size_t)T_DIM * C_DIM * 2;
  unsigned short* Wqb = (unsigned short*)(ws + off); off += (size_t)C_DIM * C_DIM * 2;
  unsigned short* Wkb = (unsigned short*)(ws + off); off += (size_t)C_DIM * C_DIM * 2;
  unsigned short* Wvb = (unsigned short*)(ws + off); off += (size_t)C_DIM * C_DIM * 2;
  unsigned short* Wob = (unsigned short*)(ws + off); off += (size_t)C_DIM * C_DIM * 2;
  unsigned short* qb  = (unsigned short*)(ws + off); off += (size_t)T_DIM * C_DIM * 2;
  unsigned short* kb  = (unsigned short*)(ws + off); off += (size_t)T_DIM * C_DIM * 2;
  unsigned short* vb  = (unsigned short*)(ws + off); off += (size_t)T_DIM * C_DIM * 2;
  unsigned short* ab  = xb;  // alias: xb dead after gemm_qkv

  // launch 1: conversion + scores
  convert_scores_kernel<<<NSCORE + NCONV, 256, 0, stream>>>(
      x, Wq, Wk, Wv, Wo, Wks, bks, xb, Wqb, Wkb, Wvb, Wob, scores);

  // launch 2: rank-sort (512 blocks) + fused QKV GEMM (768 blocks)
  gemm_qkv_rank_kernel<<<NRANK + 3 * (T_DIM / GBM) * (C_DIM / GBN), 256, 0,
                         stream>>>(
      xb, Wqb, Wkb, Wvb, bq, bk, bv, qb, kb, vb, scores, sorted);

  // launch 3: per-t top-64 selection (one wave per t)
  select_kernel<<<T_DIM / 4, 256, 0, stream>>>(sorted, selb);

  // launch 4: MFMA attention (128 t-tiles x 8 head-pairs = 1024 blocks)
  attn_kernel<<<(T_DIM / ATB) * (NH / 2), 128, 0, stream>>>(qb, kb, vb, selb, ab);

  // launch 5: output projection
  gemm_o_f32_kernel<<<(T_DIM / OBM) * (C_DIM / OBN), 256, 0, stream>>>(
      ab, Wob, bo, out);
}